// Round 1
// baseline (5178.604 us; speedup 1.0000x reference)
//
#include <hip/hip_runtime.h>
#include <hip/hip_bf16.h>

// MultiHeadAttentionLayer: B=2 S=2048 D=1024 H=16 DK=64
// Round 0: correct fp32 baseline.
//   gemm_nt: Y = X @ W^T + b  (both operands row-contiguous over k -> "NT" gemm)
//   attn_kernel: per-(b,h,64-query-block) workgroup, online softmax over 32
//                key tiles of 64, lane = key (scores) / lane = dim (PV accum),
//                second score pass for mean_atp.

#define B_  2
#define S_  2048
#define D_  1024
#define H_  16
#define DK_ 64

// ---------------------------------------------------------------- GEMM ----
#define GTS 64   // output tile 64x64
#define GKT 16   // k-tile

__global__ __launch_bounds__(256)
void gemm_nt(const float* __restrict__ X, const float* __restrict__ W,
             const float* __restrict__ bias, float* __restrict__ Y,
             int M, int N, int K, int heads_layout)
{
  __shared__ float As[GTS][GKT + 1];
  __shared__ float Bs[GTS][GKT + 1];
  const int tx = threadIdx.x;            // 0..15
  const int ty = threadIdx.y;            // 0..15
  const int tid = ty * 16 + tx;
  const int row0 = blockIdx.y * GTS;
  const int col0 = blockIdx.x * GTS;

  float acc[4][4] = {};

  for (int k0 = 0; k0 < K; k0 += GKT) {
#pragma unroll
    for (int i = 0; i < 4; i++) {
      int idx = i * 256 + tid;           // 1024 elements per tile
      int r = idx >> 4, kk = idx & 15;
      As[r][kk] = X[(size_t)(row0 + r) * K + k0 + kk];
      Bs[r][kk] = W[(size_t)(col0 + r) * K + k0 + kk];
    }
    __syncthreads();
#pragma unroll
    for (int kk = 0; kk < GKT; kk++) {
      float a[4], bb[4];
#pragma unroll
      for (int i = 0; i < 4; i++) a[i] = As[ty + 16 * i][kk];
#pragma unroll
      for (int j = 0; j < 4; j++) bb[j] = Bs[tx + 16 * j][kk];
#pragma unroll
      for (int i = 0; i < 4; i++)
#pragma unroll
        for (int j = 0; j < 4; j++)
          acc[i][j] += a[i] * bb[j];
    }
    __syncthreads();
  }

#pragma unroll
  for (int i = 0; i < 4; i++) {
    int m = row0 + ty + 16 * i;
#pragma unroll
    for (int j = 0; j < 4; j++) {
      int n = col0 + tx + 16 * j;
      float v = acc[i][j] + bias[n];
      if (heads_layout) {
        // write [B,H,S,DK]: m = b*S+s, n = h*DK+dk
        int bb2 = m / S_, s = m - bb2 * S_;
        int h = n >> 6, dk = n & 63;
        Y[((size_t)(bb2 * H_ + h) * S_ + s) * DK_ + dk] = v;
      } else {
        Y[(size_t)m * N + n] = v;
      }
    }
  }
}

// ----------------------------------------------------------- attention ----
#define QB  64   // queries per workgroup
#define KTL 64   // keys per LDS tile
#define RPW 16   // rows (queries) per wave

__device__ __forceinline__ float wave_max64(float v) {
#pragma unroll
  for (int o = 32; o > 0; o >>= 1) v = fmaxf(v, __shfl_xor(v, o, 64));
  return v;
}
__device__ __forceinline__ float wave_sum64(float v) {
#pragma unroll
  for (int o = 32; o > 0; o >>= 1) v += __shfl_xor(v, o, 64);
  return v;
}

__global__ __launch_bounds__(256)
void attn_kernel(const float* __restrict__ q_ws, const float* __restrict__ k_ws,
                 const float* __restrict__ v_ws, float* __restrict__ attn_out,
                 float* __restrict__ atp_out)
{
  __shared__ float Qs[QB][DK_];        // [row][d], reads are broadcast
  __shared__ float Kt[DK_][KTL + 1];   // transposed: [d][key], lane=key reads contiguous
  __shared__ float Vs[KTL][DK_];       // [key][d], lane=d reads contiguous
  __shared__ float atp_lds[S_];        // per-(b) key-prob partial for this WG

  const int tid  = threadIdx.x;
  const int lane = tid & 63;
  const int w    = tid >> 6;           // wave id 0..3
  const int qb   = blockIdx.x;         // 0..31
  const int h    = blockIdx.y;
  const int b    = blockIdx.z;

  const float* qg = q_ws + ((size_t)(b * H_ + h) * S_ + qb * QB) * DK_;
  const float* kg = k_ws + (size_t)(b * H_ + h) * S_ * DK_;
  const float* vg = v_ws + (size_t)(b * H_ + h) * S_ * DK_;

  // stage Q tile (64x64), contiguous
#pragma unroll
  for (int i = 0; i < QB * DK_ / 256; i++) {
    int idx = i * 256 + tid;
    Qs[idx >> 6][idx & 63] = qg[idx];
  }

  float m_r[RPW], l_r[RPW], o_r[RPW];
#pragma unroll
  for (int r = 0; r < RPW; r++) { m_r[r] = -1e30f; l_r[r] = 0.f; o_r[r] = 0.f; }

  const float scale = 12.5f;           // 100/sqrt(64)

  // ---- pass A: online softmax, O accumulation ----
  for (int kt = 0; kt < S_ / KTL; kt++) {
    __syncthreads();                   // protects Qs (kt=0) and Kt/Vs reuse
#pragma unroll
    for (int i = 0; i < KTL * DK_ / 256; i++) {
      int idx = i * 256 + tid;
      int j = idx >> 6, d = idx & 63;
      float kv = kg[(size_t)kt * KTL * DK_ + idx];
      Kt[d][j] = kv;
      Vs[j][d] = vg[(size_t)kt * KTL * DK_ + idx];
    }
    __syncthreads();

#pragma unroll
    for (int r = 0; r < RPW; r++) {
      const int row = w * RPW + r;
      // scores: lane = key j in tile
      float s = 0.f;
#pragma unroll
      for (int d0 = 0; d0 < DK_; d0 += 4) {
        float4 qv = *(const float4*)&Qs[row][d0];   // broadcast read
        s += qv.x * Kt[d0 + 0][lane];
        s += qv.y * Kt[d0 + 1][lane];
        s += qv.z * Kt[d0 + 2][lane];
        s += qv.w * Kt[d0 + 3][lane];
      }
      s *= scale;
      float tm    = wave_max64(s);
      float mnew  = fmaxf(m_r[r], tm);
      float p     = __expf(s - mnew);
      float psum  = wave_sum64(p);
      float alpha = __expf(m_r[r] - mnew);
      l_r[r] = l_r[r] * alpha + psum;
      m_r[r] = mnew;
      // O update: lane = dim d; broadcast p_j via shuffle
      float o = o_r[r] * alpha;
#pragma unroll 16
      for (int j = 0; j < KTL; j++) {
        float pj = __shfl(p, j, 64);
        o += pj * Vs[j][lane];
      }
      o_r[r] = o;
    }
  }

  // write attention output in [B,S,D] layout (pre-projection)
#pragma unroll
  for (int r = 0; r < RPW; r++) {
    int srow = qb * QB + w * RPW + r;
    attn_out[((size_t)(b * S_ + srow)) * D_ + h * DK_ + lane] = o_r[r] / l_r[r];
  }

  // ---- pass B: recompute scores for mean_atp (needs final m,l) ----
  __syncthreads();
  for (int i = tid; i < S_; i += 256) atp_lds[i] = 0.f;

  for (int kt = 0; kt < S_ / KTL; kt++) {
    __syncthreads();
#pragma unroll
    for (int i = 0; i < KTL * DK_ / 256; i++) {
      int idx = i * 256 + tid;
      Kt[idx & 63][idx >> 6] = kg[(size_t)kt * KTL * DK_ + idx];
    }
    __syncthreads();
#pragma unroll
    for (int r = 0; r < RPW; r++) {
      const int row = w * RPW + r;
      float s = 0.f;
#pragma unroll
      for (int d0 = 0; d0 < DK_; d0 += 4) {
        float4 qv = *(const float4*)&Qs[row][d0];
        s += qv.x * Kt[d0 + 0][lane];
        s += qv.y * Kt[d0 + 1][lane];
        s += qv.z * Kt[d0 + 2][lane];
        s += qv.w * Kt[d0 + 3][lane];
      }
      s *= scale;
      float p = __expf(s - m_r[r]) / l_r[r];   // true normalized prob
      atomicAdd(&atp_lds[kt * KTL + lane], p);
    }
  }
  __syncthreads();
  const float inv = 1.0f / ((float)H_ * (float)S_);
  for (int i = tid; i < S_; i += 256)
    atomicAdd(&atp_out[b * S_ + i], atp_lds[i] * inv);
}

// ------------------------------------------------------------- helpers ----
__global__ void zero_f32(float* __restrict__ p, int n) {
  int i = blockIdx.x * 256 + threadIdx.x;
  if (i < n) p[i] = 0.f;
}

// -------------------------------------------------------------- launch ----
extern "C" void kernel_launch(void* const* d_in, const int* in_sizes, int n_in,
                              void* d_out, int out_size, void* d_ws, size_t ws_size,
                              hipStream_t stream)
{
  const float* query = (const float*)d_in[0];
  const float* key_  = (const float*)d_in[1];
  const float* value = (const float*)d_in[2];
  const float* Wq = (const float*)d_in[3];
  const float* bq = (const float*)d_in[4];
  const float* Wk = (const float*)d_in[5];
  const float* bk = (const float*)d_in[6];
  const float* Wv = (const float*)d_in[7];
  const float* bv = (const float*)d_in[8];
  const float* Wo = (const float*)d_in[9];
  const float* bo = (const float*)d_in[10];

  float* out = (float*)d_out;                       // [B,S,D] flat
  float* atp = out + (size_t)B_ * S_ * D_;          // [B,S]

  float* ws   = (float*)d_ws;
  float* q_ws = ws;                                 // [B,H,S,DK]
  float* k_ws = q_ws + (size_t)B_ * S_ * D_;
  float* v_ws = k_ws + (size_t)B_ * S_ * D_;
  float* a_ws = v_ws + (size_t)B_ * S_ * D_;        // [B,S,D] pre-projection

  dim3 gblk(16, 16);
  dim3 ggrid(D_ / GTS, (B_ * S_) / GTS);

  gemm_nt<<<ggrid, gblk, 0, stream>>>(query, Wq, bq, q_ws, B_ * S_, D_, D_, 1);
  gemm_nt<<<ggrid, gblk, 0, stream>>>(key_,  Wk, bk, k_ws, B_ * S_, D_, D_, 1);
  gemm_nt<<<ggrid, gblk, 0, stream>>>(value, Wv, bv, v_ws, B_ * S_, D_, D_, 1);

  zero_f32<<<(B_ * S_ + 255) / 256, 256, 0, stream>>>(atp, B_ * S_);

  attn_kernel<<<dim3(S_ / QB, H_, B_), 256, 0, stream>>>(q_ws, k_ws, v_ws, a_ws, atp);

  gemm_nt<<<ggrid, gblk, 0, stream>>>(a_ws, Wo, bo, out, B_ * S_, D_, D_, 0);
}

// Round 3
// 1061.384 us; speedup vs baseline: 4.8791x; 4.8791x over previous
//
#include <hip/hip_runtime.h>
#include <hip/hip_bf16.h>

// MultiHeadAttentionLayer: B=2 S=2048 D=1024 H=16 DK=64
// Round 2: split-bf16 (hi+lo) MFMA flash attention.
//   bf16 scores failed (absmax 0.445): logit err ~0.6 on near-one-hot softmax.
//   Fix: q,k stored as hi+lo bf16 pairs; s = qh*kh + qh*kl + ql*kh (3x MFMA)
//   -> ~17-bit mantissa, logit err < 0.01. P,V stay plain bf16.
//   Projections remain fp32 vector GEMM (MFMA-ize next round).

#define B_  2
#define S_  2048
#define D_  1024
#define H_  16
#define DK_ 64

typedef __bf16 bf16x8 __attribute__((ext_vector_type(8)));
typedef float f32x4  __attribute__((ext_vector_type(4)));

// ---------------------------------------------------------------- GEMM ----
#define GTS 64   // output tile 64x64
#define GKT 16   // k-tile

// out_mode: 0 = fp32 [M,N] (Y)
//           1 = bf16 split [B,H,S,DK]: hi->Y, lo->Y2
//           2 = bf16 [B,H,DK,S] (V^T) -> Y
__global__ __launch_bounds__(256)
void gemm_nt(const float* __restrict__ X, const float* __restrict__ W,
             const float* __restrict__ bias, void* __restrict__ Y,
             void* __restrict__ Y2, int M, int N, int K, int out_mode)
{
  __shared__ float As[GTS][GKT + 1];
  __shared__ float Bs[GTS][GKT + 1];
  const int tx = threadIdx.x;            // 0..15
  const int ty = threadIdx.y;            // 0..15
  const int tid = ty * 16 + tx;
  const int row0 = blockIdx.y * GTS;
  const int col0 = blockIdx.x * GTS;

  float acc[4][4] = {};

  for (int k0 = 0; k0 < K; k0 += GKT) {
#pragma unroll
    for (int i = 0; i < 4; i++) {
      int idx = i * 256 + tid;           // 1024 elements per tile
      int r = idx >> 4, kk = idx & 15;
      As[r][kk] = X[(size_t)(row0 + r) * K + k0 + kk];
      Bs[r][kk] = W[(size_t)(col0 + r) * K + k0 + kk];
    }
    __syncthreads();
#pragma unroll
    for (int kk = 0; kk < GKT; kk++) {
      float a[4], bb[4];
#pragma unroll
      for (int i = 0; i < 4; i++) a[i] = As[ty + 16 * i][kk];
#pragma unroll
      for (int j = 0; j < 4; j++) bb[j] = Bs[tx + 16 * j][kk];
#pragma unroll
      for (int i = 0; i < 4; i++)
#pragma unroll
        for (int j = 0; j < 4; j++)
          acc[i][j] += a[i] * bb[j];
    }
    __syncthreads();
  }

#pragma unroll
  for (int i = 0; i < 4; i++) {
    int m = row0 + ty + 16 * i;
#pragma unroll
    for (int j = 0; j < 4; j++) {
      int n = col0 + tx + 16 * j;
      float v = acc[i][j] + bias[n];
      if (out_mode == 0) {
        ((float*)Y)[(size_t)m * N + n] = v;
      } else {
        int b2 = m / S_, s = m - b2 * S_;
        int h = n >> 6, dk = n & 63;
        if (out_mode == 1) {
          size_t off = ((size_t)(b2 * H_ + h) * S_ + s) * DK_ + dk;
          __bf16 hi = (__bf16)v;
          ((__bf16*)Y)[off]  = hi;
          ((__bf16*)Y2)[off] = (__bf16)(v - (float)hi);
        } else {
          ((__bf16*)Y)[((size_t)(b2 * H_ + h) * DK_ + dk) * S_ + s] = (__bf16)v;
        }
      }
    }
  }
}

// ----------------------------------------------------------- attention ----
// Per block: 64 queries (4 waves x 16 rows), key tiles of 64.
// LDS row stride 72 bf16 (144 B) keeps 16B alignment for b128 frag reads.
#define LSTR 72

__global__ __launch_bounds__(256)
void attn_mfma(const __bf16* __restrict__ qh_ws, const __bf16* __restrict__ ql_ws,
               const __bf16* __restrict__ kh_ws, const __bf16* __restrict__ kl_ws,
               const __bf16* __restrict__ vt_ws, float* __restrict__ attn_out,
               float* __restrict__ atp_out)
{
  __shared__ __bf16 Kh[64 * LSTR];       // [key][d] hi
  __shared__ __bf16 Kl[64 * LSTR];       // [key][d] lo
  __shared__ __bf16 Vt[64 * LSTR];       // [d][key]
  __shared__ __bf16 Ps[4][16 * LSTR];    // per-wave P tile [row][key]
  __shared__ float  atp_lds[S_];

  const int tid  = threadIdx.x;
  const int lane = tid & 63;
  const int w    = tid >> 6;             // wave 0..3
  const int c    = lane & 15;            // col-in-16 (also A-frag row m)
  const int quad = lane >> 4;            // 0..3
  const int qb   = blockIdx.x;
  const int h    = blockIdx.y;
  const int b    = blockIdx.z;

  const size_t bh = (size_t)(b * H_ + h);
  const __bf16* qhg = qh_ws + (bh * S_ + qb * 64) * DK_;
  const __bf16* qlg = ql_ws + (bh * S_ + qb * 64) * DK_;
  const __bf16* khg = kh_ws + bh * S_ * DK_;
  const __bf16* klg = kl_ws + bh * S_ * DK_;
  const __bf16* vg  = vt_ws + bh * DK_ * S_;

  // Q A-frags: A[m=lane&15][k=quad*8+j], two 32-wide k-chunks. Row = w*16+c.
  bf16x8 qhf[2], qlf[2];
  {
    const __bf16* qrow = qhg + (size_t)(w * 16 + c) * DK_;
    qhf[0] = *(const bf16x8*)(qrow + quad * 8);
    qhf[1] = *(const bf16x8*)(qrow + 32 + quad * 8);
    const __bf16* qrow2 = qlg + (size_t)(w * 16 + c) * DK_;
    qlf[0] = *(const bf16x8*)(qrow2 + quad * 8);
    qlf[1] = *(const bf16x8*)(qrow2 + 32 + quad * 8);
  }

  const float scale = 12.5f;             // 100/sqrt(64)
  float m_r[4], l_r[4];
#pragma unroll
  for (int r = 0; r < 4; r++) { m_r[r] = -1e30f; l_r[r] = 0.f; }

  // ---------------- pass 1: per-row max & sum (no PV) ----------------
  for (int kt = 0; kt < S_ / 64; kt++) {
    __syncthreads();
#pragma unroll
    for (int i = 0; i < 2; i++) {        // stage K hi+lo: 512 chunks each
      int idx = i * 256 + tid;
      int key = idx >> 3, dch = idx & 7;
      *(bf16x8*)&Kh[key * LSTR + dch * 8] =
          *(const bf16x8*)(khg + (size_t)(kt * 64 + key) * DK_ + dch * 8);
      *(bf16x8*)&Kl[key * LSTR + dch * 8] =
          *(const bf16x8*)(klg + (size_t)(kt * 64 + key) * DK_ + dch * 8);
    }
    __syncthreads();

    f32x4 sc[4];
#pragma unroll
    for (int nt = 0; nt < 4; nt++) {
      f32x4 acc = {0.f, 0.f, 0.f, 0.f};
#pragma unroll
      for (int cc = 0; cc < 2; cc++) {
        bf16x8 bh8 = *(const bf16x8*)&Kh[(nt * 16 + c) * LSTR + cc * 32 + quad * 8];
        bf16x8 bl8 = *(const bf16x8*)&Kl[(nt * 16 + c) * LSTR + cc * 32 + quad * 8];
        acc = __builtin_amdgcn_mfma_f32_16x16x32_bf16(qhf[cc], bh8, acc, 0, 0, 0);
        acc = __builtin_amdgcn_mfma_f32_16x16x32_bf16(qhf[cc], bl8, acc, 0, 0, 0);
        acc = __builtin_amdgcn_mfma_f32_16x16x32_bf16(qlf[cc], bh8, acc, 0, 0, 0);
      }
      sc[nt] = acc;
    }

    float tm[4];
#pragma unroll
    for (int r = 0; r < 4; r++) {
      tm[r] = fmaxf(fmaxf(sc[0][r], sc[1][r]), fmaxf(sc[2][r], sc[3][r]));
      tm[r] *= scale;
    }
#pragma unroll
    for (int o = 1; o < 16; o <<= 1)
#pragma unroll
      for (int r = 0; r < 4; r++) tm[r] = fmaxf(tm[r], __shfl_xor(tm[r], o, 64));

    float psum[4];
#pragma unroll
    for (int r = 0; r < 4; r++) {
      float mnew = fmaxf(m_r[r], tm[r]);
      float p = 0.f;
#pragma unroll
      for (int nt = 0; nt < 4; nt++) p += __expf(sc[nt][r] * scale - mnew);
      psum[r] = p;
      l_r[r] *= __expf(m_r[r] - mnew);   // rescale old sum
      m_r[r] = mnew;
    }
#pragma unroll
    for (int o = 1; o < 16; o <<= 1)
#pragma unroll
      for (int r = 0; r < 4; r++) psum[r] += __shfl_xor(psum[r], o, 64);
#pragma unroll
    for (int r = 0; r < 4; r++) l_r[r] += psum[r];
  }

  float rl[4];
#pragma unroll
  for (int r = 0; r < 4; r++) rl[r] = 1.0f / l_r[r];

  for (int i = tid; i < S_; i += 256) atp_lds[i] = 0.f;

  // ---------------- pass 2: final p, PV, atp ----------------
  f32x4 of[4];
#pragma unroll
  for (int nt = 0; nt < 4; nt++) of[nt] = (f32x4){0.f, 0.f, 0.f, 0.f};

  __bf16* ps = Ps[w];

  for (int kt = 0; kt < S_ / 64; kt++) {
    __syncthreads();
#pragma unroll
    for (int i = 0; i < 2; i++) {
      int idx = i * 256 + tid;
      int key = idx >> 3, dch = idx & 7;
      *(bf16x8*)&Kh[key * LSTR + dch * 8] =
          *(const bf16x8*)(khg + (size_t)(kt * 64 + key) * DK_ + dch * 8);
      *(bf16x8*)&Kl[key * LSTR + dch * 8] =
          *(const bf16x8*)(klg + (size_t)(kt * 64 + key) * DK_ + dch * 8);
      *(bf16x8*)&Vt[key * LSTR + dch * 8] =
          *(const bf16x8*)(vg + (size_t)key * S_ + kt * 64 + dch * 8);
    }
    __syncthreads();

#pragma unroll
    for (int nt = 0; nt < 4; nt++) {
      f32x4 acc = {0.f, 0.f, 0.f, 0.f};
#pragma unroll
      for (int cc = 0; cc < 2; cc++) {   // identical op order to pass 1
        bf16x8 bh8 = *(const bf16x8*)&Kh[(nt * 16 + c) * LSTR + cc * 32 + quad * 8];
        bf16x8 bl8 = *(const bf16x8*)&Kl[(nt * 16 + c) * LSTR + cc * 32 + quad * 8];
        acc = __builtin_amdgcn_mfma_f32_16x16x32_bf16(qhf[cc], bh8, acc, 0, 0, 0);
        acc = __builtin_amdgcn_mfma_f32_16x16x32_bf16(qhf[cc], bl8, acc, 0, 0, 0);
        acc = __builtin_amdgcn_mfma_f32_16x16x32_bf16(qlf[cc], bh8, acc, 0, 0, 0);
      }
      float t = 0.f;
#pragma unroll
      for (int r = 0; r < 4; r++) {
        float p = __expf(acc[r] * scale - m_r[r]) * rl[r];   // final prob
        ps[(quad * 4 + r) * LSTR + nt * 16 + c] = (__bf16)p;
        t += p;
      }
      // atp: sum over this wave's 16 rows for key nt*16+c
      t += __shfl_xor(t, 16, 64);
      t += __shfl_xor(t, 32, 64);
      if (quad == 0) atomicAdd(&atp_lds[kt * 64 + nt * 16 + c], t);
    }

    // PV: O[16q x 64d] += P[16q x 64k] @ V[64k x 64d]
#pragma unroll
    for (int nt = 0; nt < 4; nt++) {     // d-chunk
#pragma unroll
      for (int cc = 0; cc < 2; cc++) {   // key-chunk (K=32 each)
        bf16x8 pa = *(const bf16x8*)&ps[c * LSTR + cc * 32 + quad * 8];
        bf16x8 vb = *(const bf16x8*)&Vt[(nt * 16 + c) * LSTR + cc * 32 + quad * 8];
        of[nt] = __builtin_amdgcn_mfma_f32_16x16x32_bf16(pa, vb, of[nt], 0, 0, 0);
      }
    }
  }

  // write O (pre-projection) in fp32 [B,S,D]
#pragma unroll
  for (int nt = 0; nt < 4; nt++)
#pragma unroll
    for (int r = 0; r < 4; r++)
      attn_out[((size_t)(b * S_ + qb * 64 + w * 16 + quad * 4 + r)) * D_
               + h * DK_ + nt * 16 + c] = of[nt][r];

  __syncthreads();
  const float inv = 1.0f / ((float)H_ * (float)S_);
  for (int i = tid; i < S_; i += 256)
    atomicAdd(&atp_out[b * S_ + i], atp_lds[i] * inv);
}

// ------------------------------------------------------------- helpers ----
__global__ void zero_f32(float* __restrict__ p, int n) {
  int i = blockIdx.x * 256 + threadIdx.x;
  if (i < n) p[i] = 0.f;
}

// -------------------------------------------------------------- launch ----
extern "C" void kernel_launch(void* const* d_in, const int* in_sizes, int n_in,
                              void* d_out, int out_size, void* d_ws, size_t ws_size,
                              hipStream_t stream)
{
  const float* query = (const float*)d_in[0];
  const float* key_  = (const float*)d_in[1];
  const float* value = (const float*)d_in[2];
  const float* Wq = (const float*)d_in[3];
  const float* bq = (const float*)d_in[4];
  const float* Wk = (const float*)d_in[5];
  const float* bk = (const float*)d_in[6];
  const float* Wv = (const float*)d_in[7];
  const float* bv = (const float*)d_in[8];
  const float* Wo = (const float*)d_in[9];
  const float* bo = (const float*)d_in[10];

  float* out = (float*)d_out;                       // [B,S,D] flat
  float* atp = out + (size_t)B_ * S_ * D_;          // [B,S]

  const size_t NE = (size_t)B_ * S_ * D_;           // 4M elements
  __bf16* qh_ws = (__bf16*)d_ws;                    // [B,H,S,DK] hi
  __bf16* ql_ws = qh_ws + NE;                       // [B,H,S,DK] lo
  __bf16* kh_ws = ql_ws + NE;                       // [B,H,S,DK] hi
  __bf16* kl_ws = kh_ws + NE;                       // [B,H,S,DK] lo
  __bf16* vt_ws = kl_ws + NE;                       // [B,H,DK,S] (V^T)
  float*  a_ws  = (float*)(vt_ws + NE);             // [B,S,D] fp32

  dim3 gblk(16, 16);
  dim3 ggrid(D_ / GTS, (B_ * S_) / GTS);

  gemm_nt<<<ggrid, gblk, 0, stream>>>(query, Wq, bq, qh_ws, ql_ws, B_ * S_, D_, D_, 1);
  gemm_nt<<<ggrid, gblk, 0, stream>>>(key_,  Wk, bk, kh_ws, kl_ws, B_ * S_, D_, D_, 1);
  gemm_nt<<<ggrid, gblk, 0, stream>>>(value, Wv, bv, vt_ws, nullptr, B_ * S_, D_, D_, 2);

  zero_f32<<<(B_ * S_ + 255) / 256, 256, 0, stream>>>(atp, B_ * S_);

  attn_mfma<<<dim3(S_ / 64, H_, B_), 256, 0, stream>>>(qh_ws, ql_ws, kh_ws, kl_ws,
                                                       vt_ws, a_ws, atp);

  gemm_nt<<<ggrid, gblk, 0, stream>>>(a_ws, Wo, bo, out, nullptr, B_ * S_, D_, D_, 0);
}

// Round 4
// 585.950 us; speedup vs baseline: 8.8380x; 1.8114x over previous
//
#include <hip/hip_runtime.h>
#include <hip/hip_bf16.h>

// MultiHeadAttentionLayer: B=2 S=2048 D=1024 H=16 DK=64
// Round 4: MFMA projection GEMMs via 3-slot split-bf16 K-expansion.
//   Q/K proj: plain bf16 GEMM over K'=3K with slots X=[xh,xh,xl], W=[wh,wl,wh]
//     -> xh*wh + xh*wl + xl*wh per original k (~17-bit effective mantissa).
//     Epilogue writes hi+lo bf16 [B,H,S,DK] for the attention kernel.
//   V proj: plain bf16 GEMM K=1024, epilogue writes V^T bf16 [B,H,DK,S].
//   O proj: plain bf16 GEMM K=1024, fp32 output + bias.
//   Attention: unchanged split-bf16 flash kernel, now writes O as bf16.

#define B_  2
#define S_  2048
#define D_  1024
#define H_  16
#define DK_ 64

typedef __bf16 bf16x8 __attribute__((ext_vector_type(8)));
typedef float f32x4  __attribute__((ext_vector_type(4)));

// ------------------------------------------------------------ converts ----
// mode 0: X-side [hi,hi,lo]; mode 1: W-side [hi,lo,hi]
__global__ __launch_bounds__(256)
void split3_kernel(const float* __restrict__ x, __bf16* __restrict__ y,
                   int n, int mode)
{
  int i = (blockIdx.x * 256 + threadIdx.x) * 8;
  if (i >= n) return;
  float4 a = *(const float4*)(x + i);
  float4 b = *(const float4*)(x + i + 4);
  float xs[8] = {a.x, a.y, a.z, a.w, b.x, b.y, b.z, b.w};
  __bf16 out[24];
#pragma unroll
  for (int j = 0; j < 8; j++) {
    float v = xs[j];
    __bf16 hi = (__bf16)v;
    __bf16 lo = (__bf16)(v - (float)hi);
    if (mode == 0) { out[3*j] = hi; out[3*j+1] = hi; out[3*j+2] = lo; }
    else           { out[3*j] = hi; out[3*j+1] = lo; out[3*j+2] = hi; }
  }
  *(bf16x8*)(y + 3 * (size_t)i)      = *(bf16x8*)&out[0];
  *(bf16x8*)(y + 3 * (size_t)i + 8)  = *(bf16x8*)&out[8];
  *(bf16x8*)(y + 3 * (size_t)i + 16) = *(bf16x8*)&out[16];
}

__global__ __launch_bounds__(256)
void tobf16_kernel(const float* __restrict__ x, __bf16* __restrict__ y, int n)
{
  int i = (blockIdx.x * 256 + threadIdx.x) * 8;
  if (i >= n) return;
  float4 a = *(const float4*)(x + i);
  float4 b = *(const float4*)(x + i + 4);
  __bf16 out[8] = {(__bf16)a.x, (__bf16)a.y, (__bf16)a.z, (__bf16)a.w,
                   (__bf16)b.x, (__bf16)b.y, (__bf16)b.z, (__bf16)b.w};
  *(bf16x8*)(y + i) = *(bf16x8*)&out[0];
}

// ---------------------------------------------------------- MFMA GEMM ----
// Y[M,N] = X[M,K] @ W[N,K]^T + bias. 128x128 tile, 4 waves of 64x64.
// out_mode: 0 = fp32 [M,N]; 1 = bf16 hi->Y lo->Y2 in [B,H,S,DK]; 2 = bf16 V^T.
#define TM 128
#define TN 128
#define TK 64
#define KSTR 72   // LDS row stride (bf16): 144 B, keeps b128 reads conflict-light

__global__ __launch_bounds__(256)
void gemm_mfma(const __bf16* __restrict__ X, const __bf16* __restrict__ W,
               const float* __restrict__ bias, void* __restrict__ Y,
               void* __restrict__ Y2, int M, int N, int K, int out_mode)
{
  __shared__ __bf16 Xa[TM * KSTR];
  __shared__ __bf16 Wb[TN * KSTR];

  const int tid  = threadIdx.x;
  const int lane = tid & 63;
  const int w    = tid >> 6;
  const int c    = lane & 15;
  const int quad = lane >> 4;
  const int row0 = blockIdx.y * TM;
  const int col0 = blockIdx.x * TN;
  const int wr   = (w >> 1) * 64;      // wave row offset in tile
  const int wc   = (w & 1) * 64;       // wave col offset

  f32x4 acc[4][4];
#pragma unroll
  for (int i = 0; i < 4; i++)
#pragma unroll
    for (int j = 0; j < 4; j++) acc[i][j] = (f32x4){0.f, 0.f, 0.f, 0.f};

  for (int k0 = 0; k0 < K; k0 += TK) {
    __syncthreads();
#pragma unroll
    for (int i = 0; i < 4; i++) {       // 1024 chunks of 8 bf16 per tile
      int idx = i * 256 + tid;
      int r = idx >> 3, kc = idx & 7;
      *(bf16x8*)&Xa[r * KSTR + kc * 8] =
          *(const bf16x8*)(X + (size_t)(row0 + r) * K + k0 + kc * 8);
      *(bf16x8*)&Wb[r * KSTR + kc * 8] =
          *(const bf16x8*)(W + (size_t)(col0 + r) * K + k0 + kc * 8);
    }
    __syncthreads();

#pragma unroll
    for (int cc = 0; cc < 2; cc++) {
      bf16x8 af[4], bf[4];
#pragma unroll
      for (int i = 0; i < 4; i++)
        af[i] = *(const bf16x8*)&Xa[(wr + i * 16 + c) * KSTR + cc * 32 + quad * 8];
#pragma unroll
      for (int j = 0; j < 4; j++)
        bf[j] = *(const bf16x8*)&Wb[(wc + j * 16 + c) * KSTR + cc * 32 + quad * 8];
#pragma unroll
      for (int i = 0; i < 4; i++)
#pragma unroll
        for (int j = 0; j < 4; j++)
          acc[i][j] = __builtin_amdgcn_mfma_f32_16x16x32_bf16(af[i], bf[j],
                                                              acc[i][j], 0, 0, 0);
    }
  }

  // epilogue: row = row0+wr+i*16+quad*4+r, col = col0+wc+j*16+c
#pragma unroll
  for (int i = 0; i < 4; i++) {
#pragma unroll
    for (int j = 0; j < 4; j++) {
      int col = col0 + wc + j * 16 + c;
      float bcol = bias[col];
#pragma unroll
      for (int r = 0; r < 4; r++) {
        int row = row0 + wr + i * 16 + quad * 4 + r;
        float v = acc[i][j][r] + bcol;
        if (out_mode == 0) {
          ((float*)Y)[(size_t)row * N + col] = v;
        } else {
          int b2 = row >> 11, s = row & (S_ - 1);   // S_=2048
          int h = col >> 6, dk = col & 63;
          if (out_mode == 1) {
            size_t off = ((size_t)(b2 * H_ + h) * S_ + s) * DK_ + dk;
            __bf16 hi = (__bf16)v;
            ((__bf16*)Y)[off]  = hi;
            ((__bf16*)Y2)[off] = (__bf16)(v - (float)hi);
          } else {
            ((__bf16*)Y)[((size_t)(b2 * H_ + h) * DK_ + dk) * S_ + s] = (__bf16)v;
          }
        }
      }
    }
  }
}

// ----------------------------------------------------------- attention ----
#define LSTR 72

__global__ __launch_bounds__(256)
void attn_mfma(const __bf16* __restrict__ qh_ws, const __bf16* __restrict__ ql_ws,
               const __bf16* __restrict__ kh_ws, const __bf16* __restrict__ kl_ws,
               const __bf16* __restrict__ vt_ws, __bf16* __restrict__ attn_out,
               float* __restrict__ atp_out)
{
  __shared__ __bf16 Kh[64 * LSTR];       // [key][d] hi
  __shared__ __bf16 Kl[64 * LSTR];       // [key][d] lo
  __shared__ __bf16 Vt[64 * LSTR];       // [d][key]
  __shared__ __bf16 Ps[4][16 * LSTR];    // per-wave P tile [row][key]
  __shared__ float  atp_lds[S_];

  const int tid  = threadIdx.x;
  const int lane = tid & 63;
  const int w    = tid >> 6;             // wave 0..3
  const int c    = lane & 15;            // col-in-16 (also A-frag row m)
  const int quad = lane >> 4;            // 0..3
  const int qb   = blockIdx.x;
  const int h    = blockIdx.y;
  const int b    = blockIdx.z;

  const size_t bh = (size_t)(b * H_ + h);
  const __bf16* qhg = qh_ws + (bh * S_ + qb * 64) * DK_;
  const __bf16* qlg = ql_ws + (bh * S_ + qb * 64) * DK_;
  const __bf16* khg = kh_ws + bh * S_ * DK_;
  const __bf16* klg = kl_ws + bh * S_ * DK_;
  const __bf16* vg  = vt_ws + bh * DK_ * S_;

  bf16x8 qhf[2], qlf[2];
  {
    const __bf16* qrow = qhg + (size_t)(w * 16 + c) * DK_;
    qhf[0] = *(const bf16x8*)(qrow + quad * 8);
    qhf[1] = *(const bf16x8*)(qrow + 32 + quad * 8);
    const __bf16* qrow2 = qlg + (size_t)(w * 16 + c) * DK_;
    qlf[0] = *(const bf16x8*)(qrow2 + quad * 8);
    qlf[1] = *(const bf16x8*)(qrow2 + 32 + quad * 8);
  }

  const float scale = 12.5f;             // 100/sqrt(64)
  float m_r[4], l_r[4];
#pragma unroll
  for (int r = 0; r < 4; r++) { m_r[r] = -1e30f; l_r[r] = 0.f; }

  // ---------------- pass 1: per-row max & sum (no PV) ----------------
  for (int kt = 0; kt < S_ / 64; kt++) {
    __syncthreads();
#pragma unroll
    for (int i = 0; i < 2; i++) {
      int idx = i * 256 + tid;
      int key = idx >> 3, dch = idx & 7;
      *(bf16x8*)&Kh[key * LSTR + dch * 8] =
          *(const bf16x8*)(khg + (size_t)(kt * 64 + key) * DK_ + dch * 8);
      *(bf16x8*)&Kl[key * LSTR + dch * 8] =
          *(const bf16x8*)(klg + (size_t)(kt * 64 + key) * DK_ + dch * 8);
    }
    __syncthreads();

    f32x4 sc[4];
#pragma unroll
    for (int nt = 0; nt < 4; nt++) {
      f32x4 acc = {0.f, 0.f, 0.f, 0.f};
#pragma unroll
      for (int cc = 0; cc < 2; cc++) {
        bf16x8 bh8 = *(const bf16x8*)&Kh[(nt * 16 + c) * LSTR + cc * 32 + quad * 8];
        bf16x8 bl8 = *(const bf16x8*)&Kl[(nt * 16 + c) * LSTR + cc * 32 + quad * 8];
        acc = __builtin_amdgcn_mfma_f32_16x16x32_bf16(qhf[cc], bh8, acc, 0, 0, 0);
        acc = __builtin_amdgcn_mfma_f32_16x16x32_bf16(qhf[cc], bl8, acc, 0, 0, 0);
        acc = __builtin_amdgcn_mfma_f32_16x16x32_bf16(qlf[cc], bh8, acc, 0, 0, 0);
      }
      sc[nt] = acc;
    }

    float tm[4];
#pragma unroll
    for (int r = 0; r < 4; r++) {
      tm[r] = fmaxf(fmaxf(sc[0][r], sc[1][r]), fmaxf(sc[2][r], sc[3][r]));
      tm[r] *= scale;
    }
#pragma unroll
    for (int o = 1; o < 16; o <<= 1)
#pragma unroll
      for (int r = 0; r < 4; r++) tm[r] = fmaxf(tm[r], __shfl_xor(tm[r], o, 64));

    float psum[4];
#pragma unroll
    for (int r = 0; r < 4; r++) {
      float mnew = fmaxf(m_r[r], tm[r]);
      float p = 0.f;
#pragma unroll
      for (int nt = 0; nt < 4; nt++) p += __expf(sc[nt][r] * scale - mnew);
      psum[r] = p;
      l_r[r] *= __expf(m_r[r] - mnew);
      m_r[r] = mnew;
    }
#pragma unroll
    for (int o = 1; o < 16; o <<= 1)
#pragma unroll
      for (int r = 0; r < 4; r++) psum[r] += __shfl_xor(psum[r], o, 64);
#pragma unroll
    for (int r = 0; r < 4; r++) l_r[r] += psum[r];
  }

  float rl[4];
#pragma unroll
  for (int r = 0; r < 4; r++) rl[r] = 1.0f / l_r[r];

  for (int i = tid; i < S_; i += 256) atp_lds[i] = 0.f;

  // ---------------- pass 2: final p, PV, atp ----------------
  f32x4 of[4];
#pragma unroll
  for (int nt = 0; nt < 4; nt++) of[nt] = (f32x4){0.f, 0.f, 0.f, 0.f};

  __bf16* ps = Ps[w];

  for (int kt = 0; kt < S_ / 64; kt++) {
    __syncthreads();
#pragma unroll
    for (int i = 0; i < 2; i++) {
      int idx = i * 256 + tid;
      int key = idx >> 3, dch = idx & 7;
      *(bf16x8*)&Kh[key * LSTR + dch * 8] =
          *(const bf16x8*)(khg + (size_t)(kt * 64 + key) * DK_ + dch * 8);
      *(bf16x8*)&Kl[key * LSTR + dch * 8] =
          *(const bf16x8*)(klg + (size_t)(kt * 64 + key) * DK_ + dch * 8);
      *(bf16x8*)&Vt[key * LSTR + dch * 8] =
          *(const bf16x8*)(vg + (size_t)key * S_ + kt * 64 + dch * 8);
    }
    __syncthreads();

#pragma unroll
    for (int nt = 0; nt < 4; nt++) {
      f32x4 acc = {0.f, 0.f, 0.f, 0.f};
#pragma unroll
      for (int cc = 0; cc < 2; cc++) {   // identical op order to pass 1
        bf16x8 bh8 = *(const bf16x8*)&Kh[(nt * 16 + c) * LSTR + cc * 32 + quad * 8];
        bf16x8 bl8 = *(const bf16x8*)&Kl[(nt * 16 + c) * LSTR + cc * 32 + quad * 8];
        acc = __builtin_amdgcn_mfma_f32_16x16x32_bf16(qhf[cc], bh8, acc, 0, 0, 0);
        acc = __builtin_amdgcn_mfma_f32_16x16x32_bf16(qhf[cc], bl8, acc, 0, 0, 0);
        acc = __builtin_amdgcn_mfma_f32_16x16x32_bf16(qlf[cc], bh8, acc, 0, 0, 0);
      }
      float t = 0.f;
#pragma unroll
      for (int r = 0; r < 4; r++) {
        float p = __expf(acc[r] * scale - m_r[r]) * rl[r];
        ps[(quad * 4 + r) * LSTR + nt * 16 + c] = (__bf16)p;
        t += p;
      }
      t += __shfl_xor(t, 16, 64);
      t += __shfl_xor(t, 32, 64);
      if (quad == 0) atomicAdd(&atp_lds[kt * 64 + nt * 16 + c], t);
    }

#pragma unroll
    for (int nt = 0; nt < 4; nt++) {
#pragma unroll
      for (int cc = 0; cc < 2; cc++) {
        bf16x8 pa = *(const bf16x8*)&ps[c * LSTR + cc * 32 + quad * 8];
        bf16x8 vb = *(const bf16x8*)&Vt[(nt * 16 + c) * LSTR + cc * 32 + quad * 8];
        of[nt] = __builtin_amdgcn_mfma_f32_16x16x32_bf16(pa, vb, of[nt], 0, 0, 0);
      }
    }
  }

  // write O (pre-projection) as bf16 [B,S,D]
#pragma unroll
  for (int nt = 0; nt < 4; nt++)
#pragma unroll
    for (int r = 0; r < 4; r++)
      attn_out[((size_t)(b * S_ + qb * 64 + w * 16 + quad * 4 + r)) * D_
               + h * DK_ + nt * 16 + c] = (__bf16)of[nt][r];

  __syncthreads();
  const float inv = 1.0f / ((float)H_ * (float)S_);
  for (int i = tid; i < S_; i += 256)
    atomicAdd(&atp_out[b * S_ + i], atp_lds[i] * inv);
}

// ------------------------------------------------------------- helpers ----
__global__ void zero_f32(float* __restrict__ p, int n) {
  int i = blockIdx.x * 256 + threadIdx.x;
  if (i < n) p[i] = 0.f;
}

// -------------------------------------------------------------- launch ----
extern "C" void kernel_launch(void* const* d_in, const int* in_sizes, int n_in,
                              void* d_out, int out_size, void* d_ws, size_t ws_size,
                              hipStream_t stream)
{
  const float* query = (const float*)d_in[0];
  const float* key_  = (const float*)d_in[1];
  const float* value = (const float*)d_in[2];
  const float* Wq = (const float*)d_in[3];
  const float* bq = (const float*)d_in[4];
  const float* Wk = (const float*)d_in[5];
  const float* bk = (const float*)d_in[6];
  const float* Wv = (const float*)d_in[7];
  const float* bv = (const float*)d_in[8];
  const float* Wo = (const float*)d_in[9];
  const float* bo = (const float*)d_in[10];

  float* out = (float*)d_out;                       // [B,S,D] flat fp32
  float* atp = out + (size_t)B_ * S_ * D_;          // [B,S]

  const size_t NE = (size_t)B_ * S_ * D_;           // 4M
  const size_t NW = (size_t)D_ * D_;                // 1M
  __bf16* p = (__bf16*)d_ws;
  __bf16* qcat3 = p;               p += 3 * NE;     // [M, 3K] (dead after Q-GEMM)
  __bf16* kcat3 = p;               p += 3 * NE;     // [M, 3K] (dead after K-GEMM)
  __bf16* wqc3  = p;               p += 3 * NW;
  __bf16* wkc3  = p;               p += 3 * NW;
  __bf16* vxb   = p;               p += NE;
  __bf16* wvb   = p;               p += NW;
  __bf16* wob   = p;               p += NW;
  __bf16* qh_ws = p;               p += NE;
  __bf16* ql_ws = p;               p += NE;
  __bf16* kh_ws = p;               p += NE;
  __bf16* kl_ws = p;               p += NE;
  __bf16* vt_ws = kcat3;                            // alias: written disp5 > kcat3 last read disp4
  __bf16* a_ws  = qcat3;                            // alias: written disp7 > qcat3 last read disp3

  const int M = B_ * S_;

  // converts
  split3_kernel<<<NE / (256 * 8), 256, 0, stream>>>(query, qcat3, (int)NE, 0);
  split3_kernel<<<NE / (256 * 8), 256, 0, stream>>>(key_,  kcat3, (int)NE, 0);
  split3_kernel<<<NW / (256 * 8), 256, 0, stream>>>(Wq, wqc3, (int)NW, 1);
  split3_kernel<<<NW / (256 * 8), 256, 0, stream>>>(Wk, wkc3, (int)NW, 1);
  tobf16_kernel<<<NE / (256 * 8), 256, 0, stream>>>(value, vxb, (int)NE);
  tobf16_kernel<<<NW / (256 * 8), 256, 0, stream>>>(Wv, wvb, (int)NW);
  tobf16_kernel<<<NW / (256 * 8), 256, 0, stream>>>(Wo, wob, (int)NW);

  dim3 ggrid(D_ / TN, M / TM);     // (8, 32)
  gemm_mfma<<<ggrid, 256, 0, stream>>>(qcat3, wqc3, bq, qh_ws, ql_ws, M, D_, 3 * D_, 1);
  gemm_mfma<<<ggrid, 256, 0, stream>>>(kcat3, wkc3, bk, kh_ws, kl_ws, M, D_, 3 * D_, 1);
  gemm_mfma<<<ggrid, 256, 0, stream>>>(vxb,   wvb,  bv, vt_ws, nullptr, M, D_, D_, 2);

  zero_f32<<<(B_ * S_ + 255) / 256, 256, 0, stream>>>(atp, B_ * S_);

  attn_mfma<<<dim3(S_ / 64, H_, B_), 256, 0, stream>>>(qh_ws, ql_ws, kh_ws, kl_ws,
                                                       vt_ws, a_ws, atp);

  gemm_mfma<<<ggrid, 256, 0, stream>>>(a_ws, wob, bo, out, nullptr, M, D_, D_, 0);
}

// Round 5
// 543.425 us; speedup vs baseline: 9.5296x; 1.0783x over previous
//
#include <hip/hip_runtime.h>
#include <hip/hip_bf16.h>

// MultiHeadAttentionLayer: B=2 S=2048 D=1024 H=16 DK=64
// Round 5:
//   attn: QB=128 (4 waves x 32 rows), f32 Ps (kills sub-word LDS write
//         conflicts), shared score function for pass1/pass2 consistency.
//   gemm: global_load_lds (16B) staging into unpadded LDS (m97 pattern).

#define B_  2
#define S_  2048
#define D_  1024
#define H_  16
#define DK_ 64

typedef __bf16 bf16x8 __attribute__((ext_vector_type(8)));
typedef float f32x4  __attribute__((ext_vector_type(4)));

__device__ __forceinline__ void ld_g2l16(const __bf16* g, __bf16* l) {
  __builtin_amdgcn_global_load_lds(
      (const __attribute__((address_space(1))) void*)g,
      (__attribute__((address_space(3))) void*)l, 16, 0, 0);
}

// ------------------------------------------------------------ converts ----
// mode 0: X-side [hi,hi,lo]; mode 1: W-side [hi,lo,hi]
__global__ __launch_bounds__(256)
void split3_kernel(const float* __restrict__ x, __bf16* __restrict__ y,
                   int n, int mode)
{
  int i = (blockIdx.x * 256 + threadIdx.x) * 8;
  if (i >= n) return;
  float4 a = *(const float4*)(x + i);
  float4 b = *(const float4*)(x + i + 4);
  float xs[8] = {a.x, a.y, a.z, a.w, b.x, b.y, b.z, b.w};
  __bf16 out[24];
#pragma unroll
  for (int j = 0; j < 8; j++) {
    float v = xs[j];
    __bf16 hi = (__bf16)v;
    __bf16 lo = (__bf16)(v - (float)hi);
    if (mode == 0) { out[3*j] = hi; out[3*j+1] = hi; out[3*j+2] = lo; }
    else           { out[3*j] = hi; out[3*j+1] = lo; out[3*j+2] = hi; }
  }
  *(bf16x8*)(y + 3 * (size_t)i)      = *(bf16x8*)&out[0];
  *(bf16x8*)(y + 3 * (size_t)i + 8)  = *(bf16x8*)&out[8];
  *(bf16x8*)(y + 3 * (size_t)i + 16) = *(bf16x8*)&out[16];
}

__global__ __launch_bounds__(256)
void tobf16_kernel(const float* __restrict__ x, __bf16* __restrict__ y, int n)
{
  int i = (blockIdx.x * 256 + threadIdx.x) * 8;
  if (i >= n) return;
  float4 a = *(const float4*)(x + i);
  float4 b = *(const float4*)(x + i + 4);
  __bf16 out[8] = {(__bf16)a.x, (__bf16)a.y, (__bf16)a.z, (__bf16)a.w,
                   (__bf16)b.x, (__bf16)b.y, (__bf16)b.z, (__bf16)b.w};
  *(bf16x8*)(y + i) = *(bf16x8*)&out[0];
}

// ---------------------------------------------------------- MFMA GEMM ----
// Y[M,N] = X[M,K] @ W[N,K]^T + bias. 128x128 tile, 4 waves of 64x64.
// Staging via global_load_lds into unpadded [row][k] LDS (TK=64).
// out_mode: 0 = fp32 [M,N]; 1 = bf16 hi->Y lo->Y2 in [B,H,S,DK]; 2 = bf16 V^T.
#define TM 128
#define TN 128
#define TK 64

__global__ __launch_bounds__(256)
void gemm_mfma(const __bf16* __restrict__ X, const __bf16* __restrict__ W,
               const float* __restrict__ bias, void* __restrict__ Y,
               void* __restrict__ Y2, int M, int N, int K, int out_mode)
{
  __shared__ __align__(16) __bf16 Xa[TM * TK];   // 16 KB
  __shared__ __align__(16) __bf16 Wb[TN * TK];   // 16 KB

  const int tid  = threadIdx.x;
  const int lane = tid & 63;
  const int w    = tid >> 6;
  const int c    = lane & 15;
  const int quad = lane >> 4;
  const int row0 = blockIdx.y * TM;
  const int col0 = blockIdx.x * TN;
  const int wr   = (w >> 1) * 64;      // wave row offset in tile
  const int wc   = (w & 1) * 64;       // wave col offset

  f32x4 acc[4][4];
#pragma unroll
  for (int i = 0; i < 4; i++)
#pragma unroll
    for (int j = 0; j < 4; j++) acc[i][j] = (f32x4){0.f, 0.f, 0.f, 0.f};

  for (int k0 = 0; k0 < K; k0 += TK) {
    __syncthreads();                   // prior reads done before overwrite
#pragma unroll
    for (int i = 0; i < 4; i++) {      // wave w stages rows [w*32, w*32+32)
      int chunk = w * 256 + i * 64 + lane;    // 16B chunk id, 0..1023
      int r = chunk >> 3, dch = chunk & 7;
      ld_g2l16(X + (size_t)(row0 + r) * K + k0 + dch * 8, &Xa[chunk * 8]);
      ld_g2l16(W + (size_t)(col0 + r) * K + k0 + dch * 8, &Wb[chunk * 8]);
    }
    __syncthreads();                   // waits vmcnt(0) then barrier

#pragma unroll
    for (int cc = 0; cc < 2; cc++) {
      bf16x8 af[4], bf[4];
#pragma unroll
      for (int i = 0; i < 4; i++)
        af[i] = *(const bf16x8*)&Xa[(wr + i * 16 + c) * TK + cc * 32 + quad * 8];
#pragma unroll
      for (int j = 0; j < 4; j++)
        bf[j] = *(const bf16x8*)&Wb[(wc + j * 16 + c) * TK + cc * 32 + quad * 8];
#pragma unroll
      for (int i = 0; i < 4; i++)
#pragma unroll
        for (int j = 0; j < 4; j++)
          acc[i][j] = __builtin_amdgcn_mfma_f32_16x16x32_bf16(af[i], bf[j],
                                                              acc[i][j], 0, 0, 0);
    }
  }

  // epilogue: row = row0+wr+i*16+quad*4+r, col = col0+wc+j*16+c
#pragma unroll
  for (int i = 0; i < 4; i++) {
#pragma unroll
    for (int j = 0; j < 4; j++) {
      int col = col0 + wc + j * 16 + c;
      float bcol = bias[col];
#pragma unroll
      for (int r = 0; r < 4; r++) {
        int row = row0 + wr + i * 16 + quad * 4 + r;
        float v = acc[i][j][r] + bcol;
        if (out_mode == 0) {
          ((float*)Y)[(size_t)row * N + col] = v;
        } else {
          int b2 = row >> 11, s = row & (S_ - 1);   // S_=2048
          int h = col >> 6, dk = col & 63;
          if (out_mode == 1) {
            size_t off = ((size_t)(b2 * H_ + h) * S_ + s) * DK_ + dk;
            __bf16 hi = (__bf16)v;
            ((__bf16*)Y)[off]  = hi;
            ((__bf16*)Y2)[off] = (__bf16)(v - (float)hi);
          } else {
            ((__bf16*)Y)[((size_t)(b2 * H_ + h) * DK_ + dk) * S_ + s] = (__bf16)v;
          }
        }
      }
    }
  }
}

// ----------------------------------------------------------- attention ----
// QB=128 queries per block: 4 waves x 32 rows (2 row-groups of 16).
#define LSTR 72   // bf16 row stride for K/V tiles (144 B)
#define PSTR 68   // f32 row stride for P tiles

// Identical score computation for pass1/pass2 (bitwise consistency).
__device__ __forceinline__ void qk_scores(const __bf16* __restrict__ Kh,
                                          const __bf16* __restrict__ Kl,
                                          const bf16x8 qhf[2][2],
                                          const bf16x8 qlf[2][2],
                                          int c, int quad, f32x4 sc[2][4])
{
#pragma unroll
  for (int nt = 0; nt < 4; nt++) {
#pragma unroll
    for (int rg = 0; rg < 2; rg++) sc[rg][nt] = (f32x4){0.f, 0.f, 0.f, 0.f};
#pragma unroll
    for (int cc = 0; cc < 2; cc++) {
      bf16x8 bh8 = *(const bf16x8*)&Kh[(nt * 16 + c) * LSTR + cc * 32 + quad * 8];
      bf16x8 bl8 = *(const bf16x8*)&Kl[(nt * 16 + c) * LSTR + cc * 32 + quad * 8];
#pragma unroll
      for (int rg = 0; rg < 2; rg++) {
        sc[rg][nt] = __builtin_amdgcn_mfma_f32_16x16x32_bf16(qhf[rg][cc], bh8,
                                                             sc[rg][nt], 0, 0, 0);
        sc[rg][nt] = __builtin_amdgcn_mfma_f32_16x16x32_bf16(qhf[rg][cc], bl8,
                                                             sc[rg][nt], 0, 0, 0);
        sc[rg][nt] = __builtin_amdgcn_mfma_f32_16x16x32_bf16(qlf[rg][cc], bh8,
                                                             sc[rg][nt], 0, 0, 0);
      }
    }
  }
}

__global__ __launch_bounds__(256)
void attn_mfma(const __bf16* __restrict__ qh_ws, const __bf16* __restrict__ ql_ws,
               const __bf16* __restrict__ kh_ws, const __bf16* __restrict__ kl_ws,
               const __bf16* __restrict__ vt_ws, __bf16* __restrict__ attn_out,
               float* __restrict__ atp_out)
{
  __shared__ __align__(16) __bf16 Kh[64 * LSTR];   // [key][d] hi
  __shared__ __align__(16) __bf16 Kl[64 * LSTR];   // [key][d] lo
  __shared__ __align__(16) __bf16 Vt[64 * LSTR];   // [d][key]
  __shared__ __align__(16) float  Ps[4][32 * PSTR];// per-wave P (f32) [row][key]
  __shared__ float  atp_lds[S_];

  const int tid  = threadIdx.x;
  const int lane = tid & 63;
  const int w    = tid >> 6;             // wave 0..3
  const int c    = lane & 15;
  const int quad = lane >> 4;            // 0..3
  const int qb   = blockIdx.x;           // 0..15 (128 queries each)
  const int h    = blockIdx.y;
  const int b    = blockIdx.z;

  const size_t bh = (size_t)(b * H_ + h);
  const __bf16* qhg = qh_ws + (bh * S_ + qb * 128) * DK_;
  const __bf16* qlg = ql_ws + (bh * S_ + qb * 128) * DK_;
  const __bf16* khg = kh_ws + bh * S_ * DK_;
  const __bf16* klg = kl_ws + bh * S_ * DK_;
  const __bf16* vg  = vt_ws + bh * DK_ * S_;

  // Q A-frags for 2 row-groups: row = w*32 + rg*16 + c
  bf16x8 qhf[2][2], qlf[2][2];
#pragma unroll
  for (int rg = 0; rg < 2; rg++) {
    const __bf16* qrow = qhg + (size_t)(w * 32 + rg * 16 + c) * DK_;
    qhf[rg][0] = *(const bf16x8*)(qrow + quad * 8);
    qhf[rg][1] = *(const bf16x8*)(qrow + 32 + quad * 8);
    const __bf16* qrow2 = qlg + (size_t)(w * 32 + rg * 16 + c) * DK_;
    qlf[rg][0] = *(const bf16x8*)(qrow2 + quad * 8);
    qlf[rg][1] = *(const bf16x8*)(qrow2 + 32 + quad * 8);
  }

  const float scale = 12.5f;             // 100/sqrt(64)
  float m_r[2][4], l_r[2][4];
#pragma unroll
  for (int rg = 0; rg < 2; rg++)
#pragma unroll
    for (int r = 0; r < 4; r++) { m_r[rg][r] = -1e30f; l_r[rg][r] = 0.f; }

  // ---------------- pass 1: per-row max & sum (no PV) ----------------
  for (int kt = 0; kt < S_ / 64; kt++) {
    __syncthreads();
#pragma unroll
    for (int i = 0; i < 2; i++) {        // 512 chunks of 8 bf16 per tile
      int idx = i * 256 + tid;
      int key = idx >> 3, dch = idx & 7;
      *(bf16x8*)&Kh[key * LSTR + dch * 8] =
          *(const bf16x8*)(khg + (size_t)(kt * 64 + key) * DK_ + dch * 8);
      *(bf16x8*)&Kl[key * LSTR + dch * 8] =
          *(const bf16x8*)(klg + (size_t)(kt * 64 + key) * DK_ + dch * 8);
    }
    __syncthreads();

    f32x4 sc[2][4];
    qk_scores(Kh, Kl, qhf, qlf, c, quad, sc);

    float tm[2][4], psum[2][4];
#pragma unroll
    for (int rg = 0; rg < 2; rg++)
#pragma unroll
      for (int r = 0; r < 4; r++) {
        tm[rg][r] = fmaxf(fmaxf(sc[rg][0][r], sc[rg][1][r]),
                          fmaxf(sc[rg][2][r], sc[rg][3][r])) * scale;
      }
#pragma unroll
    for (int o = 1; o < 16; o <<= 1)
#pragma unroll
      for (int rg = 0; rg < 2; rg++)
#pragma unroll
        for (int r = 0; r < 4; r++)
          tm[rg][r] = fmaxf(tm[rg][r], __shfl_xor(tm[rg][r], o, 64));

#pragma unroll
    for (int rg = 0; rg < 2; rg++)
#pragma unroll
      for (int r = 0; r < 4; r++) {
        float mnew = fmaxf(m_r[rg][r], tm[rg][r]);
        float p = 0.f;
#pragma unroll
        for (int nt = 0; nt < 4; nt++) p += __expf(sc[rg][nt][r] * scale - mnew);
        psum[rg][r] = p;
        l_r[rg][r] *= __expf(m_r[rg][r] - mnew);
        m_r[rg][r] = mnew;
      }
#pragma unroll
    for (int o = 1; o < 16; o <<= 1)
#pragma unroll
      for (int rg = 0; rg < 2; rg++)
#pragma unroll
        for (int r = 0; r < 4; r++)
          psum[rg][r] += __shfl_xor(psum[rg][r], o, 64);
#pragma unroll
    for (int rg = 0; rg < 2; rg++)
#pragma unroll
      for (int r = 0; r < 4; r++) l_r[rg][r] += psum[rg][r];
  }

  float rl[2][4];
#pragma unroll
  for (int rg = 0; rg < 2; rg++)
#pragma unroll
    for (int r = 0; r < 4; r++) rl[rg][r] = 1.0f / l_r[rg][r];

  for (int i = tid; i < S_; i += 256) atp_lds[i] = 0.f;

  // ---------------- pass 2: final p, PV, atp ----------------
  f32x4 of[2][4];
#pragma unroll
  for (int rg = 0; rg < 2; rg++)
#pragma unroll
    for (int nt = 0; nt < 4; nt++) of[rg][nt] = (f32x4){0.f, 0.f, 0.f, 0.f};

  float* ps = Ps[w];

  for (int kt = 0; kt < S_ / 64; kt++) {
    __syncthreads();
#pragma unroll
    for (int i = 0; i < 2; i++) {
      int idx = i * 256 + tid;
      int key = idx >> 3, dch = idx & 7;
      *(bf16x8*)&Kh[key * LSTR + dch * 8] =
          *(const bf16x8*)(khg + (size_t)(kt * 64 + key) * DK_ + dch * 8);
      *(bf16x8*)&Kl[key * LSTR + dch * 8] =
          *(const bf16x8*)(klg + (size_t)(kt * 64 + key) * DK_ + dch * 8);
      *(bf16x8*)&Vt[key * LSTR + dch * 8] =
          *(const bf16x8*)(vg + (size_t)key * S_ + kt * 64 + dch * 8);
    }
    __syncthreads();

    f32x4 sc[2][4];
    qk_scores(Kh, Kl, qhf, qlf, c, quad, sc);

#pragma unroll
    for (int nt = 0; nt < 4; nt++) {
      float t = 0.f;
#pragma unroll
      for (int rg = 0; rg < 2; rg++)
#pragma unroll
        for (int r = 0; r < 4; r++) {
          float p = __expf(sc[rg][nt][r] * scale - m_r[rg][r]) * rl[rg][r];
          ps[(rg * 16 + quad * 4 + r) * PSTR + nt * 16 + c] = p;
          t += p;
        }
      t += __shfl_xor(t, 16, 64);
      t += __shfl_xor(t, 32, 64);
      if (quad == 0) atomicAdd(&atp_lds[kt * 64 + nt * 16 + c], t);
    }

    // PV: O[32q x 64d] += P[32q x 64k] @ V[64k x 64d]
#pragma unroll
    for (int rg = 0; rg < 2; rg++) {
      bf16x8 pa[2];
#pragma unroll
      for (int cc = 0; cc < 2; cc++) {
        const float* pp = &ps[(rg * 16 + c) * PSTR + cc * 32 + quad * 8];
        f32x4 p0 = *(const f32x4*)pp;
        f32x4 p1 = *(const f32x4*)(pp + 4);
        bf16x8 v8;
#pragma unroll
        for (int j = 0; j < 4; j++) { v8[j] = (__bf16)p0[j]; v8[4 + j] = (__bf16)p1[j]; }
        pa[cc] = v8;
      }
#pragma unroll
      for (int nt = 0; nt < 4; nt++)
#pragma unroll
        for (int cc = 0; cc < 2; cc++) {
          bf16x8 vb = *(const bf16x8*)&Vt[(nt * 16 + c) * LSTR + cc * 32 + quad * 8];
          of[rg][nt] = __builtin_amdgcn_mfma_f32_16x16x32_bf16(pa[cc], vb,
                                                               of[rg][nt], 0, 0, 0);
        }
    }
  }

  // write O (pre-projection) as bf16 [B,S,D]
#pragma unroll
  for (int rg = 0; rg < 2; rg++)
#pragma unroll
    for (int nt = 0; nt < 4; nt++)
#pragma unroll
      for (int r = 0; r < 4; r++)
        attn_out[((size_t)(b * S_ + qb * 128 + w * 32 + rg * 16 + quad * 4 + r)) * D_
                 + h * DK_ + nt * 16 + c] = (__bf16)of[rg][nt][r];

  __syncthreads();
  const float inv = 1.0f / ((float)H_ * (float)S_);
  for (int i = tid; i < S_; i += 256)
    atomicAdd(&atp_out[b * S_ + i], atp_lds[i] * inv);
}

// ------------------------------------------------------------- helpers ----
__global__ void zero_f32(float* __restrict__ p, int n) {
  int i = blockIdx.x * 256 + threadIdx.x;
  if (i < n) p[i] = 0.f;
}

// -------------------------------------------------------------- launch ----
extern "C" void kernel_launch(void* const* d_in, const int* in_sizes, int n_in,
                              void* d_out, int out_size, void* d_ws, size_t ws_size,
                              hipStream_t stream)
{
  const float* query = (const float*)d_in[0];
  const float* key_  = (const float*)d_in[1];
  const float* value = (const float*)d_in[2];
  const float* Wq = (const float*)d_in[3];
  const float* bq = (const float*)d_in[4];
  const float* Wk = (const float*)d_in[5];
  const float* bk = (const float*)d_in[6];
  const float* Wv = (const float*)d_in[7];
  const float* bv = (const float*)d_in[8];
  const float* Wo = (const float*)d_in[9];
  const float* bo = (const float*)d_in[10];

  float* out = (float*)d_out;                       // [B,S,D] flat fp32
  float* atp = out + (size_t)B_ * S_ * D_;          // [B,S]

  const size_t NE = (size_t)B_ * S_ * D_;           // 4M
  const size_t NW = (size_t)D_ * D_;                // 1M
  __bf16* p = (__bf16*)d_ws;
  __bf16* qcat3 = p;               p += 3 * NE;     // dead after Q-GEMM
  __bf16* kcat3 = p;               p += 3 * NE;     // dead after K-GEMM
  __bf16* wqc3  = p;               p += 3 * NW;
  __bf16* wkc3  = p;               p += 3 * NW;
  __bf16* vxb   = p;               p += NE;
  __bf16* wvb   = p;               p += NW;
  __bf16* wob   = p;               p += NW;
  __bf16* qh_ws = p;               p += NE;
  __bf16* ql_ws = p;               p += NE;
  __bf16* kh_ws = p;               p += NE;
  __bf16* kl_ws = p;               p += NE;
  __bf16* vt_ws = kcat3;                            // alias (dead before write)
  __bf16* a_ws  = qcat3;                            // alias (dead before write)

  const int M = B_ * S_;

  split3_kernel<<<NE / (256 * 8), 256, 0, stream>>>(query, qcat3, (int)NE, 0);
  split3_kernel<<<NE / (256 * 8), 256, 0, stream>>>(key_,  kcat3, (int)NE, 0);
  split3_kernel<<<NW / (256 * 8), 256, 0, stream>>>(Wq, wqc3, (int)NW, 1);
  split3_kernel<<<NW / (256 * 8), 256, 0, stream>>>(Wk, wkc3, (int)NW, 1);
  tobf16_kernel<<<NE / (256 * 8), 256, 0, stream>>>(value, vxb, (int)NE);
  tobf16_kernel<<<NW / (256 * 8), 256, 0, stream>>>(Wv, wvb, (int)NW);
  tobf16_kernel<<<NW / (256 * 8), 256, 0, stream>>>(Wo, wob, (int)NW);

  dim3 ggrid(D_ / TN, M / TM);     // (8, 32)
  gemm_mfma<<<ggrid, 256, 0, stream>>>(qcat3, wqc3, bq, qh_ws, ql_ws, M, D_, 3 * D_, 1);
  gemm_mfma<<<ggrid, 256, 0, stream>>>(kcat3, wkc3, bk, kh_ws, kl_ws, M, D_, 3 * D_, 1);
  gemm_mfma<<<ggrid, 256, 0, stream>>>(vxb,   wvb,  bv, vt_ws, nullptr, M, D_, D_, 2);

  zero_f32<<<(B_ * S_ + 255) / 256, 256, 0, stream>>>(atp, B_ * S_);

  attn_mfma<<<dim3(S_ / 128, H_, B_), 256, 0, stream>>>(qh_ws, ql_ws, kh_ws, kl_ws,
                                                        vt_ws, a_ws, atp);

  gemm_mfma<<<ggrid, 256, 0, stream>>>(a_ws, wob, bo, out, nullptr, M, D_, D_, 0);
}

// Round 6
// 511.323 us; speedup vs baseline: 10.1279x; 1.0628x over previous
//
#include <hip/hip_runtime.h>
#include <hip/hip_bf16.h>

// MultiHeadAttentionLayer: B=2 S=2048 D=1024 H=16 DK=64
// Round 6:
//   gemm: TM=64 -> 512 blocks (2-3/CU co-resident; round-5's 256 blocks = 1/CU
//         exposed the global_load_lds barrier drain).
//   converts: all 7 fused into one dispatch (launch-gap savings).
//   attn: Ps halved to 16 rows reused per row-group (per-wave buffer, no
//         barrier) -> LDS 53 KB, 3 blocks/CU; scale*log2e folded into q at
//         the Q-GEMM epilogue -> exp2f, no per-score muls.

#define B_  2
#define S_  2048
#define D_  1024
#define H_  16
#define DK_ 64

typedef __bf16 bf16x8 __attribute__((ext_vector_type(8)));
typedef float f32x4  __attribute__((ext_vector_type(4)));

__device__ __forceinline__ void ld_g2l16(const __bf16* g, __bf16* l) {
  __builtin_amdgcn_global_load_lds(
      (const __attribute__((address_space(1))) void*)g,
      (__attribute__((address_space(3))) void*)l, 16, 0, 0);
}

// ------------------------------------------------------------ converts ----
__device__ __forceinline__ void split3_body(const float* __restrict__ x,
                                            __bf16* __restrict__ y,
                                            int lbid, int tid, int mode)
{
  int i = (lbid * 256 + tid) * 8;
  float4 a = *(const float4*)(x + i);
  float4 b = *(const float4*)(x + i + 4);
  float xs[8] = {a.x, a.y, a.z, a.w, b.x, b.y, b.z, b.w};
  __bf16 out[24];
#pragma unroll
  for (int j = 0; j < 8; j++) {
    float v = xs[j];
    __bf16 hi = (__bf16)v;
    __bf16 lo = (__bf16)(v - (float)hi);
    if (mode == 0) { out[3*j] = hi; out[3*j+1] = hi; out[3*j+2] = lo; }
    else           { out[3*j] = hi; out[3*j+1] = lo; out[3*j+2] = hi; }
  }
  *(bf16x8*)(y + 3 * (size_t)i)      = *(bf16x8*)&out[0];
  *(bf16x8*)(y + 3 * (size_t)i + 8)  = *(bf16x8*)&out[8];
  *(bf16x8*)(y + 3 * (size_t)i + 16) = *(bf16x8*)&out[16];
}

__device__ __forceinline__ void tobf16_body(const float* __restrict__ x,
                                            __bf16* __restrict__ y,
                                            int lbid, int tid)
{
  int i = (lbid * 256 + tid) * 8;
  float4 a = *(const float4*)(x + i);
  float4 b = *(const float4*)(x + i + 4);
  __bf16 out[8] = {(__bf16)a.x, (__bf16)a.y, (__bf16)a.z, (__bf16)a.w,
                   (__bf16)b.x, (__bf16)b.y, (__bf16)b.z, (__bf16)b.w};
  *(bf16x8*)(y + i) = *(bf16x8*)&out[0];
}

// job ranges (blocks of 2048 elements): q 2048 | k 2048 | v 2048 | Wq 512 |
// Wk 512 | Wv 512 | Wo 512  -> 8192 blocks total
__global__ __launch_bounds__(256)
void convert_all(const float* __restrict__ query, const float* __restrict__ key_,
                 const float* __restrict__ value, const float* __restrict__ Wq,
                 const float* __restrict__ Wk, const float* __restrict__ Wv,
                 const float* __restrict__ Wo, __bf16* __restrict__ qcat3,
                 __bf16* __restrict__ kcat3, __bf16* __restrict__ vxb,
                 __bf16* __restrict__ wqc3, __bf16* __restrict__ wkc3,
                 __bf16* __restrict__ wvb, __bf16* __restrict__ wob)
{
  int bid = blockIdx.x, tid = threadIdx.x;
  if (bid < 2048)       split3_body(query, qcat3, bid, tid, 0);
  else if (bid < 4096)  split3_body(key_,  kcat3, bid - 2048, tid, 0);
  else if (bid < 6144)  tobf16_body(value, vxb,   bid - 4096, tid);
  else if (bid < 6656)  split3_body(Wq, wqc3, bid - 6144, tid, 1);
  else if (bid < 7168)  split3_body(Wk, wkc3, bid - 6656, tid, 1);
  else if (bid < 7680)  tobf16_body(Wv, wvb, bid - 7168, tid);
  else                  tobf16_body(Wo, wob, bid - 7680, tid);
}

// ---------------------------------------------------------- MFMA GEMM ----
// Y[M,N] = osf*(X[M,K] @ W[N,K]^T + bias). 64x128 tile, 4 waves of 64x32.
// out_mode: 0 = fp32 [M,N]; 1 = bf16 hi->Y lo->Y2 in [B,H,S,DK]; 2 = bf16 V^T.
#define TM 64
#define TN 128
#define TK 64

__global__ __launch_bounds__(256)
void gemm_mfma(const __bf16* __restrict__ X, const __bf16* __restrict__ W,
               const float* __restrict__ bias, void* __restrict__ Y,
               void* __restrict__ Y2, int M, int N, int K, int out_mode,
               float osf)
{
  __shared__ __align__(16) __bf16 Xa[TM * TK];   // 8 KB
  __shared__ __align__(16) __bf16 Wb[TN * TK];   // 16 KB

  const int tid  = threadIdx.x;
  const int lane = tid & 63;
  const int w    = tid >> 6;
  const int c    = lane & 15;
  const int quad = lane >> 4;
  const int row0 = blockIdx.y * TM;
  const int col0 = blockIdx.x * TN;
  const int wc   = w * 32;             // wave col offset

  f32x4 acc[4][2];
#pragma unroll
  for (int i = 0; i < 4; i++)
#pragma unroll
    for (int j = 0; j < 2; j++) acc[i][j] = (f32x4){0.f, 0.f, 0.f, 0.f};

  for (int k0 = 0; k0 < K; k0 += TK) {
    __syncthreads();
#pragma unroll
    for (int i = 0; i < 2; i++) {      // Xa: 512 chunks of 16B
      int chunk = i * 256 + w * 64 + lane;
      int r = chunk >> 3, dch = chunk & 7;
      ld_g2l16(X + (size_t)(row0 + r) * K + k0 + dch * 8, &Xa[chunk * 8]);
    }
#pragma unroll
    for (int i = 0; i < 4; i++) {      // Wb: 1024 chunks
      int chunk = i * 256 + w * 64 + lane;
      int r = chunk >> 3, dch = chunk & 7;
      ld_g2l16(W + (size_t)(col0 + r) * K + k0 + dch * 8, &Wb[chunk * 8]);
    }
    __syncthreads();

#pragma unroll
    for (int cc = 0; cc < 2; cc++) {
      bf16x8 af[4], bf[2];
#pragma unroll
      for (int i = 0; i < 4; i++)
        af[i] = *(const bf16x8*)&Xa[(i * 16 + c) * TK + cc * 32 + quad * 8];
#pragma unroll
      for (int j = 0; j < 2; j++)
        bf[j] = *(const bf16x8*)&Wb[(wc + j * 16 + c) * TK + cc * 32 + quad * 8];
#pragma unroll
      for (int i = 0; i < 4; i++)
#pragma unroll
        for (int j = 0; j < 2; j++)
          acc[i][j] = __builtin_amdgcn_mfma_f32_16x16x32_bf16(af[i], bf[j],
                                                              acc[i][j], 0, 0, 0);
    }
  }

#pragma unroll
  for (int i = 0; i < 4; i++) {
#pragma unroll
    for (int j = 0; j < 2; j++) {
      int col = col0 + wc + j * 16 + c;
      float bcol = bias[col];
#pragma unroll
      for (int r = 0; r < 4; r++) {
        int row = row0 + i * 16 + quad * 4 + r;
        float v = (acc[i][j][r] + bcol) * osf;
        if (out_mode == 0) {
          ((float*)Y)[(size_t)row * N + col] = v;
        } else {
          int b2 = row >> 11, s = row & (S_ - 1);
          int h = col >> 6, dk = col & 63;
          if (out_mode == 1) {
            size_t off = ((size_t)(b2 * H_ + h) * S_ + s) * DK_ + dk;
            __bf16 hi = (__bf16)v;
            ((__bf16*)Y)[off]  = hi;
            ((__bf16*)Y2)[off] = (__bf16)(v - (float)hi);
          } else {
            ((__bf16*)Y)[((size_t)(b2 * H_ + h) * DK_ + dk) * S_ + s] = (__bf16)v;
          }
        }
      }
    }
  }
}

// ----------------------------------------------------------- attention ----
// QB=128 queries per block: 4 waves x 32 rows (2 row-groups of 16).
// q is pre-scaled by 12.5*log2(e) -> scores are in log2 domain; use exp2f.
#define LSTR 72   // bf16 row stride for K/V tiles (144 B)
#define PSTR 68   // f32 row stride for P tiles (16 rows, reused per rg)

__device__ __forceinline__ void qk_scores(const __bf16* __restrict__ Kh,
                                          const __bf16* __restrict__ Kl,
                                          const bf16x8 qhf[2][2],
                                          const bf16x8 qlf[2][2],
                                          int c, int quad, f32x4 sc[2][4])
{
#pragma unroll
  for (int nt = 0; nt < 4; nt++) {
#pragma unroll
    for (int rg = 0; rg < 2; rg++) sc[rg][nt] = (f32x4){0.f, 0.f, 0.f, 0.f};
#pragma unroll
    for (int cc = 0; cc < 2; cc++) {
      bf16x8 bh8 = *(const bf16x8*)&Kh[(nt * 16 + c) * LSTR + cc * 32 + quad * 8];
      bf16x8 bl8 = *(const bf16x8*)&Kl[(nt * 16 + c) * LSTR + cc * 32 + quad * 8];
#pragma unroll
      for (int rg = 0; rg < 2; rg++) {
        sc[rg][nt] = __builtin_amdgcn_mfma_f32_16x16x32_bf16(qhf[rg][cc], bh8,
                                                             sc[rg][nt], 0, 0, 0);
        sc[rg][nt] = __builtin_amdgcn_mfma_f32_16x16x32_bf16(qhf[rg][cc], bl8,
                                                             sc[rg][nt], 0, 0, 0);
        sc[rg][nt] = __builtin_amdgcn_mfma_f32_16x16x32_bf16(qlf[rg][cc], bh8,
                                                             sc[rg][nt], 0, 0, 0);
      }
    }
  }
}

__global__ __launch_bounds__(256)
void attn_mfma(const __bf16* __restrict__ qh_ws, const __bf16* __restrict__ ql_ws,
               const __bf16* __restrict__ kh_ws, const __bf16* __restrict__ kl_ws,
               const __bf16* __restrict__ vt_ws, __bf16* __restrict__ attn_out,
               float* __restrict__ atp_out)
{
  __shared__ __align__(16) __bf16 Kh[64 * LSTR];   // [key][d] hi
  __shared__ __align__(16) __bf16 Kl[64 * LSTR];   // [key][d] lo
  __shared__ __align__(16) __bf16 Vt[64 * LSTR];   // [d][key]
  __shared__ __align__(16) float  Ps[4][16 * PSTR];// per-wave P (f32), 16 rows
  __shared__ float  atp_lds[S_];

  const int tid  = threadIdx.x;
  const int lane = tid & 63;
  const int w    = tid >> 6;
  const int c    = lane & 15;
  const int quad = lane >> 4;
  const int qb   = blockIdx.x;           // 0..15
  const int h    = blockIdx.y;
  const int b    = blockIdx.z;

  const size_t bh = (size_t)(b * H_ + h);
  const __bf16* qhg = qh_ws + (bh * S_ + qb * 128) * DK_;
  const __bf16* qlg = ql_ws + (bh * S_ + qb * 128) * DK_;
  const __bf16* khg = kh_ws + bh * S_ * DK_;
  const __bf16* klg = kl_ws + bh * S_ * DK_;
  const __bf16* vg  = vt_ws + bh * DK_ * S_;

  bf16x8 qhf[2][2], qlf[2][2];
#pragma unroll
  for (int rg = 0; rg < 2; rg++) {
    const __bf16* qrow = qhg + (size_t)(w * 32 + rg * 16 + c) * DK_;
    qhf[rg][0] = *(const bf16x8*)(qrow + quad * 8);
    qhf[rg][1] = *(const bf16x8*)(qrow + 32 + quad * 8);
    const __bf16* qrow2 = qlg + (size_t)(w * 32 + rg * 16 + c) * DK_;
    qlf[rg][0] = *(const bf16x8*)(qrow2 + quad * 8);
    qlf[rg][1] = *(const bf16x8*)(qrow2 + 32 + quad * 8);
  }

  float m_r[2][4], l_r[2][4];
#pragma unroll
  for (int rg = 0; rg < 2; rg++)
#pragma unroll
    for (int r = 0; r < 4; r++) { m_r[rg][r] = -1e30f; l_r[rg][r] = 0.f; }

  // ---------------- pass 1: per-row max & sum (log2 domain) ----------------
  for (int kt = 0; kt < S_ / 64; kt++) {
    __syncthreads();
#pragma unroll
    for (int i = 0; i < 2; i++) {
      int idx = i * 256 + tid;
      int key = idx >> 3, dch = idx & 7;
      *(bf16x8*)&Kh[key * LSTR + dch * 8] =
          *(const bf16x8*)(khg + (size_t)(kt * 64 + key) * DK_ + dch * 8);
      *(bf16x8*)&Kl[key * LSTR + dch * 8] =
          *(const bf16x8*)(klg + (size_t)(kt * 64 + key) * DK_ + dch * 8);
    }
    __syncthreads();

    f32x4 sc[2][4];
    qk_scores(Kh, Kl, qhf, qlf, c, quad, sc);

    float tm[2][4], psum[2][4];
#pragma unroll
    for (int rg = 0; rg < 2; rg++)
#pragma unroll
      for (int r = 0; r < 4; r++)
        tm[rg][r] = fmaxf(fmaxf(sc[rg][0][r], sc[rg][1][r]),
                          fmaxf(sc[rg][2][r], sc[rg][3][r]));
#pragma unroll
    for (int o = 1; o < 16; o <<= 1)
#pragma unroll
      for (int rg = 0; rg < 2; rg++)
#pragma unroll
        for (int r = 0; r < 4; r++)
          tm[rg][r] = fmaxf(tm[rg][r], __shfl_xor(tm[rg][r], o, 64));

#pragma unroll
    for (int rg = 0; rg < 2; rg++)
#pragma unroll
      for (int r = 0; r < 4; r++) {
        float mnew = fmaxf(m_r[rg][r], tm[rg][r]);
        float p = 0.f;
#pragma unroll
        for (int nt = 0; nt < 4; nt++) p += exp2f(sc[rg][nt][r] - mnew);
        psum[rg][r] = p;
        l_r[rg][r] *= exp2f(m_r[rg][r] - mnew);
        m_r[rg][r] = mnew;
      }
#pragma unroll
    for (int o = 1; o < 16; o <<= 1)
#pragma unroll
      for (int rg = 0; rg < 2; rg++)
#pragma unroll
        for (int r = 0; r < 4; r++)
          psum[rg][r] += __shfl_xor(psum[rg][r], o, 64);
#pragma unroll
    for (int rg = 0; rg < 2; rg++)
#pragma unroll
      for (int r = 0; r < 4; r++) l_r[rg][r] += psum[rg][r];
  }

  float rl[2][4];
#pragma unroll
  for (int rg = 0; rg < 2; rg++)
#pragma unroll
    for (int r = 0; r < 4; r++) rl[rg][r] = 1.0f / l_r[rg][r];

  for (int i = tid; i < S_; i += 256) atp_lds[i] = 0.f;

  // ---------------- pass 2: final p, PV, atp ----------------
  f32x4 of[2][4];
#pragma unroll
  for (int rg = 0; rg < 2; rg++)
#pragma unroll
    for (int nt = 0; nt < 4; nt++) of[rg][nt] = (f32x4){0.f, 0.f, 0.f, 0.f};

  float* ps = Ps[w];

  for (int kt = 0; kt < S_ / 64; kt++) {
    __syncthreads();
#pragma unroll
    for (int i = 0; i < 2; i++) {
      int idx = i * 256 + tid;
      int key = idx >> 3, dch = idx & 7;
      *(bf16x8*)&Kh[key * LSTR + dch * 8] =
          *(const bf16x8*)(khg + (size_t)(kt * 64 + key) * DK_ + dch * 8);
      *(bf16x8*)&Kl[key * LSTR + dch * 8] =
          *(const bf16x8*)(klg + (size_t)(kt * 64 + key) * DK_ + dch * 8);
      *(bf16x8*)&Vt[key * LSTR + dch * 8] =
          *(const bf16x8*)(vg + (size_t)key * S_ + kt * 64 + dch * 8);
    }
    __syncthreads();

    f32x4 sc[2][4];
    qk_scores(Kh, Kl, qhf, qlf, c, quad, sc);

    float t[4] = {0.f, 0.f, 0.f, 0.f};
#pragma unroll
    for (int rg = 0; rg < 2; rg++) {
      // write 16-row P tile (f32, per-wave; reused for both rg)
#pragma unroll
      for (int nt = 0; nt < 4; nt++)
#pragma unroll
        for (int r = 0; r < 4; r++) {
          float p = exp2f(sc[rg][nt][r] - m_r[rg][r]) * rl[rg][r];
          ps[(quad * 4 + r) * PSTR + nt * 16 + c] = p;
          t[nt] += p;
        }
      // PV for this row-group
      bf16x8 pa[2];
#pragma unroll
      for (int cc = 0; cc < 2; cc++) {
        const float* pp = &ps[c * PSTR + cc * 32 + quad * 8];
        f32x4 p0 = *(const f32x4*)pp;
        f32x4 p1 = *(const f32x4*)(pp + 4);
        bf16x8 v8;
#pragma unroll
        for (int j = 0; j < 4; j++) { v8[j] = (__bf16)p0[j]; v8[4 + j] = (__bf16)p1[j]; }
        pa[cc] = v8;
      }
#pragma unroll
      for (int nt = 0; nt < 4; nt++)
#pragma unroll
        for (int cc = 0; cc < 2; cc++) {
          bf16x8 vb = *(const bf16x8*)&Vt[(nt * 16 + c) * LSTR + cc * 32 + quad * 8];
          of[rg][nt] = __builtin_amdgcn_mfma_f32_16x16x32_bf16(pa[cc], vb,
                                                               of[rg][nt], 0, 0, 0);
        }
    }

#pragma unroll
    for (int nt = 0; nt < 4; nt++) {
      float tt = t[nt];
      tt += __shfl_xor(tt, 16, 64);
      tt += __shfl_xor(tt, 32, 64);
      if (quad == 0) atomicAdd(&atp_lds[kt * 64 + nt * 16 + c], tt);
    }
  }

  // write O (pre-projection) as bf16 [B,S,D]
#pragma unroll
  for (int rg = 0; rg < 2; rg++)
#pragma unroll
    for (int nt = 0; nt < 4; nt++)
#pragma unroll
      for (int r = 0; r < 4; r++)
        attn_out[((size_t)(b * S_ + qb * 128 + w * 32 + rg * 16 + quad * 4 + r)) * D_
                 + h * DK_ + nt * 16 + c] = (__bf16)of[rg][nt][r];

  __syncthreads();
  const float inv = 1.0f / ((float)H_ * (float)S_);
  for (int i = tid; i < S_; i += 256)
    atomicAdd(&atp_out[b * S_ + i], atp_lds[i] * inv);
}

// ------------------------------------------------------------- helpers ----
__global__ void zero_f32(float* __restrict__ p, int n) {
  int i = blockIdx.x * 256 + threadIdx.x;
  if (i < n) p[i] = 0.f;
}

// -------------------------------------------------------------- launch ----
extern "C" void kernel_launch(void* const* d_in, const int* in_sizes, int n_in,
                              void* d_out, int out_size, void* d_ws, size_t ws_size,
                              hipStream_t stream)
{
  const float* query = (const float*)d_in[0];
  const float* key_  = (const float*)d_in[1];
  const float* value = (const float*)d_in[2];
  const float* Wq = (const float*)d_in[3];
  const float* bq = (const float*)d_in[4];
  const float* Wk = (const float*)d_in[5];
  const float* bk = (const float*)d_in[6];
  const float* Wv = (const float*)d_in[7];
  const float* bv = (const float*)d_in[8];
  const float* Wo = (const float*)d_in[9];
  const float* bo = (const float*)d_in[10];

  float* out = (float*)d_out;                       // [B,S,D] flat fp32
  float* atp = out + (size_t)B_ * S_ * D_;          // [B,S]

  const size_t NE = (size_t)B_ * S_ * D_;           // 4M
  const size_t NW = (size_t)D_ * D_;                // 1M
  __bf16* p = (__bf16*)d_ws;
  __bf16* qcat3 = p;               p += 3 * NE;     // dead after Q-GEMM
  __bf16* kcat3 = p;               p += 3 * NE;     // dead after K-GEMM
  __bf16* wqc3  = p;               p += 3 * NW;
  __bf16* wkc3  = p;               p += 3 * NW;
  __bf16* vxb   = p;               p += NE;
  __bf16* wvb   = p;               p += NW;
  __bf16* wob   = p;               p += NW;
  __bf16* qh_ws = p;               p += NE;
  __bf16* ql_ws = p;               p += NE;
  __bf16* kh_ws = p;               p += NE;
  __bf16* kl_ws = p;               p += NE;
  __bf16* vt_ws = kcat3;                            // alias (dead before write)
  __bf16* a_ws  = qcat3;                            // alias (dead before write)

  const int M = B_ * S_;
  const float QSF = 18.0337320f;   // 12.5 * log2(e) -> scores in log2 domain

  convert_all<<<8192, 256, 0, stream>>>(query, key_, value, Wq, Wk, Wv, Wo,
                                        qcat3, kcat3, vxb, wqc3, wkc3, wvb, wob);

  dim3 ggrid(D_ / TN, M / TM);     // (8, 64) = 512 blocks
  gemm_mfma<<<ggrid, 256, 0, stream>>>(qcat3, wqc3, bq, qh_ws, ql_ws, M, D_, 3 * D_, 1, QSF);
  gemm_mfma<<<ggrid, 256, 0, stream>>>(kcat3, wkc3, bk, kh_ws, kl_ws, M, D_, 3 * D_, 1, 1.0f);
  gemm_mfma<<<ggrid, 256, 0, stream>>>(vxb,   wvb,  bv, vt_ws, nullptr, M, D_, D_, 2, 1.0f);

  zero_f32<<<(B_ * S_ + 255) / 256, 256, 0, stream>>>(atp, B_ * S_);

  attn_mfma<<<dim3(S_ / 128, H_, B_), 256, 0, stream>>>(qh_ws, ql_ws, kh_ws, kl_ws,
                                                        vt_ws, a_ws, atp);

  gemm_mfma<<<ggrid, 256, 0, stream>>>(a_ws, wob, bo, out, nullptr, M, D_, D_, 0, 1.0f);
}

// Round 7
// 480.736 us; speedup vs baseline: 10.7722x; 1.0636x over previous
//
#include <hip/hip_runtime.h>
#include <hip/hip_bf16.h>

// MultiHeadAttentionLayer: B=2 S=2048 D=1024 H=16 DK=64
// Round 7:
//   attn: 512 threads (8 waves x 16 rows, QB=128). Grid is fixed at 512
//         blocks (2/CU) so occupancy must come from waves/block: 8 waves
//         doubles waves/CU to 16. z = m + log2(l) -> pass2 p = exp2(s-z).
//   launches: convert_all (+atp zero) | gemm_qkv (fused Q,K,V via grid.z) |
//             attn | gemm_o  -> 4 dispatches.

#define B_  2
#define S_  2048
#define D_  1024
#define H_  16
#define DK_ 64

typedef __bf16 bf16x8 __attribute__((ext_vector_type(8)));
typedef float f32x4  __attribute__((ext_vector_type(4)));

__device__ __forceinline__ void ld_g2l16(const __bf16* g, __bf16* l) {
  __builtin_amdgcn_global_load_lds(
      (const __attribute__((address_space(1))) void*)g,
      (__attribute__((address_space(3))) void*)l, 16, 0, 0);
}

// ------------------------------------------------------------ converts ----
__device__ __forceinline__ void split3_body(const float* __restrict__ x,
                                            __bf16* __restrict__ y,
                                            int lbid, int tid, int mode)
{
  int i = (lbid * 256 + tid) * 8;
  float4 a = *(const float4*)(x + i);
  float4 b = *(const float4*)(x + i + 4);
  float xs[8] = {a.x, a.y, a.z, a.w, b.x, b.y, b.z, b.w};
  __bf16 out[24];
#pragma unroll
  for (int j = 0; j < 8; j++) {
    float v = xs[j];
    __bf16 hi = (__bf16)v;
    __bf16 lo = (__bf16)(v - (float)hi);
    if (mode == 0) { out[3*j] = hi; out[3*j+1] = hi; out[3*j+2] = lo; }
    else           { out[3*j] = hi; out[3*j+1] = lo; out[3*j+2] = hi; }
  }
  *(bf16x8*)(y + 3 * (size_t)i)      = *(bf16x8*)&out[0];
  *(bf16x8*)(y + 3 * (size_t)i + 8)  = *(bf16x8*)&out[8];
  *(bf16x8*)(y + 3 * (size_t)i + 16) = *(bf16x8*)&out[16];
}

__device__ __forceinline__ void tobf16_body(const float* __restrict__ x,
                                            __bf16* __restrict__ y,
                                            int lbid, int tid)
{
  int i = (lbid * 256 + tid) * 8;
  float4 a = *(const float4*)(x + i);
  float4 b = *(const float4*)(x + i + 4);
  __bf16 out[8] = {(__bf16)a.x, (__bf16)a.y, (__bf16)a.z, (__bf16)a.w,
                   (__bf16)b.x, (__bf16)b.y, (__bf16)b.z, (__bf16)b.w};
  *(bf16x8*)(y + i) = *(bf16x8*)&out[0];
}

// block ranges (2048 elems each): q 2048 | k 2048 | v 2048 | Wq 512 | Wk 512 |
// Wv 512 | Wo 512 | atp-zero 2  -> 8194 blocks
__global__ __launch_bounds__(256)
void convert_all(const float* __restrict__ query, const float* __restrict__ key_,
                 const float* __restrict__ value, const float* __restrict__ Wq,
                 const float* __restrict__ Wk, const float* __restrict__ Wv,
                 const float* __restrict__ Wo, __bf16* __restrict__ qcat3,
                 __bf16* __restrict__ kcat3, __bf16* __restrict__ vxb,
                 __bf16* __restrict__ wqc3, __bf16* __restrict__ wkc3,
                 __bf16* __restrict__ wvb, __bf16* __restrict__ wob,
                 float* __restrict__ atp)
{
  int bid = blockIdx.x, tid = threadIdx.x;
  if (bid < 2048)       split3_body(query, qcat3, bid, tid, 0);
  else if (bid < 4096)  split3_body(key_,  kcat3, bid - 2048, tid, 0);
  else if (bid < 6144)  tobf16_body(value, vxb,   bid - 4096, tid);
  else if (bid < 6656)  split3_body(Wq, wqc3, bid - 6144, tid, 1);
  else if (bid < 7168)  split3_body(Wk, wkc3, bid - 6656, tid, 1);
  else if (bid < 7680)  tobf16_body(Wv, wvb, bid - 7168, tid);
  else if (bid < 8192)  tobf16_body(Wo, wob, bid - 7680, tid);
  else {
    int base = (bid - 8192) * 2048;
#pragma unroll
    for (int j = 0; j < 8; j++) atp[base + j * 256 + tid] = 0.f;
  }
}

// ---------------------------------------------------------- MFMA GEMM ----
// Y[M,N] = osf*(X[M,K] @ W[N,K]^T + bias). 64x128 tile, 4 waves of 64x32.
// out_mode: 0 = fp32 [M,N]; 1 = bf16 hi->Y lo->Y2 in [B,H,S,DK]; 2 = bf16 V^T.
#define TM 64
#define TN 128
#define TK 64

__device__ __forceinline__
void gemm_body(const __bf16* __restrict__ X, const __bf16* __restrict__ W,
               const float* __restrict__ bias, void* __restrict__ Y,
               void* __restrict__ Y2, int N, int K, int out_mode, float osf,
               __bf16* Xa, __bf16* Wb, int bx, int by)
{
  const int tid  = threadIdx.x;
  const int lane = tid & 63;
  const int w    = tid >> 6;
  const int c    = lane & 15;
  const int quad = lane >> 4;
  const int row0 = by * TM;
  const int col0 = bx * TN;
  const int wc   = w * 32;

  f32x4 acc[4][2];
#pragma unroll
  for (int i = 0; i < 4; i++)
#pragma unroll
    for (int j = 0; j < 2; j++) acc[i][j] = (f32x4){0.f, 0.f, 0.f, 0.f};

  for (int k0 = 0; k0 < K; k0 += TK) {
    __syncthreads();
#pragma unroll
    for (int i = 0; i < 2; i++) {      // Xa: 512 chunks of 16B
      int chunk = i * 256 + w * 64 + lane;
      int r = chunk >> 3, dch = chunk & 7;
      ld_g2l16(X + (size_t)(row0 + r) * K + k0 + dch * 8, &Xa[chunk * 8]);
    }
#pragma unroll
    for (int i = 0; i < 4; i++) {      // Wb: 1024 chunks
      int chunk = i * 256 + w * 64 + lane;
      int r = chunk >> 3, dch = chunk & 7;
      ld_g2l16(W + (size_t)(col0 + r) * K + k0 + dch * 8, &Wb[chunk * 8]);
    }
    __syncthreads();

#pragma unroll
    for (int cc = 0; cc < 2; cc++) {
      bf16x8 af[4], bf[2];
#pragma unroll
      for (int i = 0; i < 4; i++)
        af[i] = *(const bf16x8*)&Xa[(i * 16 + c) * TK + cc * 32 + quad * 8];
#pragma unroll
      for (int j = 0; j < 2; j++)
        bf[j] = *(const bf16x8*)&Wb[(wc + j * 16 + c) * TK + cc * 32 + quad * 8];
#pragma unroll
      for (int i = 0; i < 4; i++)
#pragma unroll
        for (int j = 0; j < 2; j++)
          acc[i][j] = __builtin_amdgcn_mfma_f32_16x16x32_bf16(af[i], bf[j],
                                                              acc[i][j], 0, 0, 0);
    }
  }

#pragma unroll
  for (int i = 0; i < 4; i++) {
#pragma unroll
    for (int j = 0; j < 2; j++) {
      int col = col0 + wc + j * 16 + c;
      float bcol = bias[col];
#pragma unroll
      for (int r = 0; r < 4; r++) {
        int row = row0 + i * 16 + quad * 4 + r;
        float v = (acc[i][j][r] + bcol) * osf;
        if (out_mode == 0) {
          ((float*)Y)[(size_t)row * N + col] = v;
        } else {
          int b2 = row >> 11, s = row & (S_ - 1);
          int h = col >> 6, dk = col & 63;
          if (out_mode == 1) {
            size_t off = ((size_t)(b2 * H_ + h) * S_ + s) * DK_ + dk;
            __bf16 hi = (__bf16)v;
            ((__bf16*)Y)[off]  = hi;
            ((__bf16*)Y2)[off] = (__bf16)(v - (float)hi);
          } else {
            ((__bf16*)Y)[((size_t)(b2 * H_ + h) * DK_ + dk) * S_ + s] = (__bf16)v;
          }
        }
      }
    }
  }
}

// fused Q/K/V projections: blockIdx.z selects the job
__global__ __launch_bounds__(256)
void gemm_qkv(const __bf16* __restrict__ qcat3, const __bf16* __restrict__ wqc3,
              const float* __restrict__ bq, __bf16* __restrict__ qh, __bf16* __restrict__ ql,
              const __bf16* __restrict__ kcat3, const __bf16* __restrict__ wkc3,
              const float* __restrict__ bk, __bf16* __restrict__ kh, __bf16* __restrict__ kl,
              const __bf16* __restrict__ vxb, const __bf16* __restrict__ wvb,
              const float* __restrict__ bv, __bf16* __restrict__ vt, float qsf)
{
  __shared__ __align__(16) __bf16 Xa[TM * TK];
  __shared__ __align__(16) __bf16 Wb[TN * TK];
  int z = blockIdx.z;
  if (z == 0)
    gemm_body(qcat3, wqc3, bq, qh, ql, D_, 3 * D_, 1, qsf, Xa, Wb, blockIdx.x, blockIdx.y);
  else if (z == 1)
    gemm_body(kcat3, wkc3, bk, kh, kl, D_, 3 * D_, 1, 1.0f, Xa, Wb, blockIdx.x, blockIdx.y);
  else
    gemm_body(vxb, wvb, bv, vt, nullptr, D_, D_, 2, 1.0f, Xa, Wb, blockIdx.x, blockIdx.y);
}

__global__ __launch_bounds__(256)
void gemm_mfma(const __bf16* __restrict__ X, const __bf16* __restrict__ W,
               const float* __restrict__ bias, void* __restrict__ Y,
               void* __restrict__ Y2, int M, int N, int K, int out_mode,
               float osf)
{
  __shared__ __align__(16) __bf16 Xa[TM * TK];
  __shared__ __align__(16) __bf16 Wb[TN * TK];
  gemm_body(X, W, bias, Y, Y2, N, K, out_mode, osf, Xa, Wb, blockIdx.x, blockIdx.y);
}

// ----------------------------------------------------------- attention ----
// QB=128 queries per block: 8 waves x 16 rows. 512 threads.
// q pre-scaled by 12.5*log2(e) -> log2-domain scores, exp2f.
#define LSTR 72   // bf16 row stride for K/V tiles (144 B)
#define PSTR 68   // f32 row stride for P tiles

__device__ __forceinline__ void qk_scores(const __bf16* __restrict__ Kh,
                                          const __bf16* __restrict__ Kl,
                                          const bf16x8 qhf[2],
                                          const bf16x8 qlf[2],
                                          int c, int quad, f32x4 sc[4])
{
#pragma unroll
  for (int nt = 0; nt < 4; nt++) {
    sc[nt] = (f32x4){0.f, 0.f, 0.f, 0.f};
#pragma unroll
    for (int cc = 0; cc < 2; cc++) {
      bf16x8 bh8 = *(const bf16x8*)&Kh[(nt * 16 + c) * LSTR + cc * 32 + quad * 8];
      bf16x8 bl8 = *(const bf16x8*)&Kl[(nt * 16 + c) * LSTR + cc * 32 + quad * 8];
      sc[nt] = __builtin_amdgcn_mfma_f32_16x16x32_bf16(qhf[cc], bh8, sc[nt], 0, 0, 0);
      sc[nt] = __builtin_amdgcn_mfma_f32_16x16x32_bf16(qhf[cc], bl8, sc[nt], 0, 0, 0);
      sc[nt] = __builtin_amdgcn_mfma_f32_16x16x32_bf16(qlf[cc], bh8, sc[nt], 0, 0, 0);
    }
  }
}

__global__ __launch_bounds__(512)
void attn_mfma(const __bf16* __restrict__ qh_ws, const __bf16* __restrict__ ql_ws,
               const __bf16* __restrict__ kh_ws, const __bf16* __restrict__ kl_ws,
               const __bf16* __restrict__ vt_ws, __bf16* __restrict__ attn_out,
               float* __restrict__ atp_out)
{
  __shared__ __align__(16) __bf16 Kh[64 * LSTR];    // [key][d] hi
  __shared__ __align__(16) __bf16 Kl[64 * LSTR];    // [key][d] lo
  __shared__ __align__(16) __bf16 Vt[64 * LSTR];    // [d][key]
  __shared__ __align__(16) float  Ps[8][16 * PSTR]; // per-wave P (f32)
  __shared__ float  atp_lds[S_];

  const int tid  = threadIdx.x;
  const int lane = tid & 63;
  const int w    = tid >> 6;             // wave 0..7
  const int c    = lane & 15;
  const int quad = lane >> 4;
  const int qb   = blockIdx.x;           // 0..15
  const int h    = blockIdx.y;
  const int b    = blockIdx.z;

  const size_t bh = (size_t)(b * H_ + h);
  const __bf16* qhg = qh_ws + (bh * S_ + qb * 128) * DK_;
  const __bf16* qlg = ql_ws + (bh * S_ + qb * 128) * DK_;
  const __bf16* khg = kh_ws + bh * S_ * DK_;
  const __bf16* klg = kl_ws + bh * S_ * DK_;
  const __bf16* vg  = vt_ws + bh * DK_ * S_;

  // Q A-frags: row = w*16 + c
  bf16x8 qhf[2], qlf[2];
  {
    const __bf16* qrow = qhg + (size_t)(w * 16 + c) * DK_;
    qhf[0] = *(const bf16x8*)(qrow + quad * 8);
    qhf[1] = *(const bf16x8*)(qrow + 32 + quad * 8);
    const __bf16* qrow2 = qlg + (size_t)(w * 16 + c) * DK_;
    qlf[0] = *(const bf16x8*)(qrow2 + quad * 8);
    qlf[1] = *(const bf16x8*)(qrow2 + 32 + quad * 8);
  }

  float m_r[4], l_r[4];
#pragma unroll
  for (int r = 0; r < 4; r++) { m_r[r] = -1e30f; l_r[r] = 0.f; }

  // ---------------- pass 1: per-row max & sum (log2 domain) ----------------
  for (int kt = 0; kt < S_ / 64; kt++) {
    __syncthreads();
    {
      int key = tid >> 3, dch = tid & 7;   // 512 chunks per tile
      *(bf16x8*)&Kh[key * LSTR + dch * 8] =
          *(const bf16x8*)(khg + (size_t)(kt * 64 + key) * DK_ + dch * 8);
      *(bf16x8*)&Kl[key * LSTR + dch * 8] =
          *(const bf16x8*)(klg + (size_t)(kt * 64 + key) * DK_ + dch * 8);
    }
    __syncthreads();

    f32x4 sc[4];
    qk_scores(Kh, Kl, qhf, qlf, c, quad, sc);

    float tm[4], psum[4];
#pragma unroll
    for (int r = 0; r < 4; r++)
      tm[r] = fmaxf(fmaxf(sc[0][r], sc[1][r]), fmaxf(sc[2][r], sc[3][r]));
#pragma unroll
    for (int o = 1; o < 16; o <<= 1)
#pragma unroll
      for (int r = 0; r < 4; r++)
        tm[r] = fmaxf(tm[r], __shfl_xor(tm[r], o, 64));

#pragma unroll
    for (int r = 0; r < 4; r++) {
      float mnew = fmaxf(m_r[r], tm[r]);
      float p = 0.f;
#pragma unroll
      for (int nt = 0; nt < 4; nt++) p += exp2f(sc[nt][r] - mnew);
      psum[r] = p;
      l_r[r] *= exp2f(m_r[r] - mnew);
      m_r[r] = mnew;
    }
#pragma unroll
    for (int o = 1; o < 16; o <<= 1)
#pragma unroll
      for (int r = 0; r < 4; r++)
        psum[r] += __shfl_xor(psum[r], o, 64);
#pragma unroll
    for (int r = 0; r < 4; r++) l_r[r] += psum[r];
  }

  // z = m + log2(l): p = exp2(s - z) is the final prob
  float z_r[4];
#pragma unroll
  for (int r = 0; r < 4; r++) z_r[r] = m_r[r] + log2f(l_r[r]);

  for (int i = tid; i < S_; i += 512) atp_lds[i] = 0.f;

  // ---------------- pass 2: final p, PV, atp ----------------
  f32x4 of[4];
#pragma unroll
  for (int nt = 0; nt < 4; nt++) of[nt] = (f32x4){0.f, 0.f, 0.f, 0.f};

  float* ps = Ps[w];

  for (int kt = 0; kt < S_ / 64; kt++) {
    __syncthreads();
    {
      int key = tid >> 3, dch = tid & 7;
      *(bf16x8*)&Kh[key * LSTR + dch * 8] =
          *(const bf16x8*)(khg + (size_t)(kt * 64 + key) * DK_ + dch * 8);
      *(bf16x8*)&Kl[key * LSTR + dch * 8] =
          *(const bf16x8*)(klg + (size_t)(kt * 64 + key) * DK_ + dch * 8);
      *(bf16x8*)&Vt[key * LSTR + dch * 8] =
          *(const bf16x8*)(vg + (size_t)key * S_ + kt * 64 + dch * 8);
    }
    __syncthreads();

    f32x4 sc[4];
    qk_scores(Kh, Kl, qhf, qlf, c, quad, sc);

    float t[4];
#pragma unroll
    for (int nt = 0; nt < 4; nt++) {
      t[nt] = 0.f;
#pragma unroll
      for (int r = 0; r < 4; r++) {
        float p = exp2f(sc[nt][r] - z_r[r]);   // final prob
        ps[(quad * 4 + r) * PSTR + nt * 16 + c] = p;
        t[nt] += p;
      }
    }

    // PV A-frags from Ps (f32 -> bf16)
    bf16x8 pa[2];
#pragma unroll
    for (int cc = 0; cc < 2; cc++) {
      const float* pp = &ps[c * PSTR + cc * 32 + quad * 8];
      f32x4 p0 = *(const f32x4*)pp;
      f32x4 p1 = *(const f32x4*)(pp + 4);
      bf16x8 v8;
#pragma unroll
      for (int j = 0; j < 4; j++) { v8[j] = (__bf16)p0[j]; v8[4 + j] = (__bf16)p1[j]; }
      pa[cc] = v8;
    }
#pragma unroll
    for (int nt = 0; nt < 4; nt++)
#pragma unroll
      for (int cc = 0; cc < 2; cc++) {
        bf16x8 vb = *(const bf16x8*)&Vt[(nt * 16 + c) * LSTR + cc * 32 + quad * 8];
        of[nt] = __builtin_amdgcn_mfma_f32_16x16x32_bf16(pa[cc], vb, of[nt], 0, 0, 0);
      }

#pragma unroll
    for (int nt = 0; nt < 4; nt++) {
      float tt = t[nt];
      tt += __shfl_xor(tt, 16, 64);
      tt += __shfl_xor(tt, 32, 64);
      if (quad == 0) atomicAdd(&atp_lds[kt * 64 + nt * 16 + c], tt);
    }
  }

  // write O (pre-projection) as bf16 [B,S,D]
#pragma unroll
  for (int nt = 0; nt < 4; nt++)
#pragma unroll
    for (int r = 0; r < 4; r++)
      attn_out[((size_t)(b * S_ + qb * 128 + w * 16 + quad * 4 + r)) * D_
               + h * DK_ + nt * 16 + c] = (__bf16)of[nt][r];

  __syncthreads();
  const float inv = 1.0f / ((float)H_ * (float)S_);
  for (int i = tid; i < S_; i += 512)
    atomicAdd(&atp_out[b * S_ + i], atp_lds[i] * inv);
}

// -------------------------------------------------------------- launch ----
extern "C" void kernel_launch(void* const* d_in, const int* in_sizes, int n_in,
                              void* d_out, int out_size, void* d_ws, size_t ws_size,
                              hipStream_t stream)
{
  const float* query = (const float*)d_in[0];
  const float* key_  = (const float*)d_in[1];
  const float* value = (const float*)d_in[2];
  const float* Wq = (const float*)d_in[3];
  const float* bq = (const float*)d_in[4];
  const float* Wk = (const float*)d_in[5];
  const float* bk = (const float*)d_in[6];
  const float* Wv = (const float*)d_in[7];
  const float* bv = (const float*)d_in[8];
  const float* Wo = (const float*)d_in[9];
  const float* bo = (const float*)d_in[10];

  float* out = (float*)d_out;                       // [B,S,D] flat fp32
  float* atp = out + (size_t)B_ * S_ * D_;          // [B,S]

  const size_t NE = (size_t)B_ * S_ * D_;           // 4M
  const size_t NW = (size_t)D_ * D_;                // 1M
  __bf16* p = (__bf16*)d_ws;
  __bf16* qcat3 = p;               p += 3 * NE;     // dead after Q-GEMM
  __bf16* kcat3 = p;               p += 3 * NE;     // dead after K-GEMM
  __bf16* wqc3  = p;               p += 3 * NW;
  __bf16* wkc3  = p;               p += 3 * NW;
  __bf16* vxb   = p;               p += NE;
  __bf16* wvb   = p;               p += NW;
  __bf16* wob   = p;               p += NW;
  __bf16* qh_ws = p;               p += NE;
  __bf16* ql_ws = p;               p += NE;
  __bf16* kh_ws = p;               p += NE;
  __bf16* kl_ws = p;               p += NE;
  __bf16* vt_ws = kcat3;                            // alias (dead before write)
  __bf16* a_ws  = qcat3;                            // alias (dead before write)

  const int M = B_ * S_;
  const float QSF = 18.0337320f;   // 12.5 * log2(e) -> log2-domain scores

  convert_all<<<8194, 256, 0, stream>>>(query, key_, value, Wq, Wk, Wv, Wo,
                                        qcat3, kcat3, vxb, wqc3, wkc3, wvb, wob,
                                        atp);

  gemm_qkv<<<dim3(D_ / TN, M / TM, 3), 256, 0, stream>>>(
      qcat3, wqc3, bq, qh_ws, ql_ws,
      kcat3, wkc3, bk, kh_ws, kl_ws,
      vxb,   wvb,  bv, vt_ws, QSF);

  attn_mfma<<<dim3(S_ / 128, H_, B_), 512, 0, stream>>>(qh_ws, ql_ws, kh_ws, kl_ws,
                                                        vt_ws, a_ws, atp);

  gemm_mfma<<<dim3(D_ / TN, M / TM), 256, 0, stream>>>(a_ws, wob, bo, out, nullptr,
                                                       M, D_, D_, 0, 1.0f);
}